// Round 6
// baseline (901.210 us; speedup 1.0000x reference)
//
#include <hip/hip_runtime.h>

typedef __attribute__((ext_vector_type(8))) _Float16 f16x8;
typedef __attribute__((ext_vector_type(4))) _Float16 f16x4;
typedef __attribute__((ext_vector_type(4))) float f32x4;

#define DI __device__ __forceinline__
// Raw barrier: LDS-drain only (lgkmcnt). Avoids the compiler's vmcnt(0) drain.
#define BAR() asm volatile("s_waitcnt lgkmcnt(0)\n\ts_barrier" ::: "memory")

DI f32x4 mfma16(f16x8 a, f16x8 b, f32x4 c) {
    return __builtin_amdgcn_mfma_f32_16x16x32_f16(a, b, c, 0, 0, 0);
}

// Wave-mapping (4-wave kernels): wave w owns features [w*32, w*32+32) for layers
// 0/1; layer 2: wave w -> rows (w>>1)*16 (+32*g), cols (w&1)*16.
// PROVEN STATE (R10, 504 us): lb(256,3), 64-row k_edge/k_enc/k_dec, 32-row k_node.
// R11 lesson: lb(256,4) caps regs at 128 -> weights evicted -> regression.
// R12 lesson: 64-row k_node diverged intermittently under graph replay -> revert.
// R13/R15 lesson: register-held gather prefetch spills regardless of waves_per_eu.
// R14 lesson: LDS shrink for 4 blocks/CU: achieved occupancy FELL; extra BAR -5%.
// R16 lesson: DMA prefetch (global_load_lds) clean (no spill, conflicts -25%) but
//   dur 54 vs 51.5 -> staging latency is NOT the critical path. All three staging
//   attacks neutral/negative => the limiter is serial-chain stalls at 3 waves/SIMD.
// R17 (this round): TLP attack. k_edge goes 8 waves (512 thr), same 64-row tile,
//   same total MFMA/LDS work: wave w = feature slice (w&3)*32, row half (w>>2)*32
//   for l0/l1; l2 splits (w>>1) rows x (w&1) cols, no gg loop. 3 blocks/CU ->
//   24 waves/CU (6/SIMD, was 3). lb(512,6) pins the <=84-reg tier (weights 72).

template <int NK>
DI void load_wf2(const _Float16* __restrict__ wt, int Kp, int nbase, int l16, int q,
                 f16x8 f[NK][2]) {
#pragma unroll
    for (int nt = 0; nt < 2; ++nt) {
        int n = nbase + nt * 16 + l16;
#pragma unroll
        for (int ks = 0; ks < NK; ++ks)
            f[ks][nt] = *(const f16x8*)(wt + n * Kp + ks * 32 + q * 8);
    }
}

// Layer 0 over MH 16-row groups starting at row-group mb: H0' = relu(W0^T X^T).
// nb = feature base (halves). f16 out to H0 (stride 136). BAR.
template <int NK0, int MH>
DI void l0(const f16x8 (*w0f)[2], const _Float16* __restrict__ X, int xstride,
           _Float16* __restrict__ H0, int l16, int nb, int mb, int q) {
    const f32x4 zero = {0.f, 0.f, 0.f, 0.f};
    f32x4 acc[2][MH];
#pragma unroll
    for (int nt = 0; nt < 2; ++nt)
#pragma unroll
        for (int mt = 0; mt < MH; ++mt) acc[nt][mt] = zero;
#pragma unroll
    for (int ks = 0; ks < NK0; ++ks) {
        f16x8 x[MH];
#pragma unroll
        for (int mt = 0; mt < MH; ++mt)
            x[mt] = *(const f16x8*)(X + ((mb + mt) * 16 + l16) * xstride + ks * 32 + q * 8);
#pragma unroll
        for (int nt = 0; nt < 2; ++nt)
#pragma unroll
            for (int mt = 0; mt < MH; ++mt)
                acc[nt][mt] = mfma16(w0f[ks][nt], x[mt], acc[nt][mt]);
    }
#pragma unroll
    for (int mt = 0; mt < MH; ++mt)
#pragma unroll
        for (int nt = 0; nt < 2; ++nt) {
            f16x4 h;
#pragma unroll
            for (int i = 0; i < 4; ++i) h[i] = (_Float16)fmaxf(acc[nt][mt][i], 0.f);
            *(f16x4*)(H0 + ((mb + mt) * 16 + l16) * 136 + nb + nt * 16 + q * 4) = h;
        }
    BAR();
}

// Layer 1: H1' = relu(W1^T H0^T) over the same row groups. BAR.
template <int MH>
DI void l1(const f16x8 (*w1f)[2], const _Float16* __restrict__ H0,
           _Float16* __restrict__ H1, int l16, int nb, int mb, int q) {
    const f32x4 zero = {0.f, 0.f, 0.f, 0.f};
    f32x4 a1[2][MH];
#pragma unroll
    for (int nt = 0; nt < 2; ++nt)
#pragma unroll
        for (int mt = 0; mt < MH; ++mt) a1[nt][mt] = zero;
#pragma unroll
    for (int ks = 0; ks < 4; ++ks) {
        f16x8 x[MH];
#pragma unroll
        for (int mt = 0; mt < MH; ++mt)
            x[mt] = *(const f16x8*)(H0 + ((mb + mt) * 16 + l16) * 136 + ks * 32 + q * 8);
#pragma unroll
        for (int nt = 0; nt < 2; ++nt)
#pragma unroll
            for (int mt = 0; mt < MH; ++mt)
                a1[nt][mt] = mfma16(w1f[ks][nt], x[mt], a1[nt][mt]);
    }
#pragma unroll
    for (int mt = 0; mt < MH; ++mt)
#pragma unroll
        for (int nt = 0; nt < 2; ++nt) {
            f16x4 h;
#pragma unroll
            for (int i = 0; i < 4; ++i) h[i] = (_Float16)fmaxf(a1[nt][mt][i], 0.f);
            *(f16x4*)(H1 + ((mb + mt) * 16 + l16) * 136 + nb + nt * 16 + q * 4) = h;
        }
    BAR();
}

// Layer 2, row group g: rows (w>>1)*16 + l16 + 32*g, cols (w&1)*16 + q*4 + i.
DI f32x4 l2g(const f16x8* w2f, const _Float16* __restrict__ H1, int l16, int w,
             int q, int g) {
    int m = (w >> 1) * 16 + l16 + 32 * g;
    f32x4 acc = {0.f, 0.f, 0.f, 0.f};
#pragma unroll
    for (int ks = 0; ks < 4; ++ks) {
        f16x8 x = *(const f16x8*)(H1 + m * 136 + ks * 32 + q * 8);
        acc = mfma16(w2f[ks], x, acc);
    }
    return acc;
}

// ---------------- weight prep: fp32 [K][N] -> f16 W^T [Np][Kp] (zero padded) ----
struct WPtrs { const float* p[15]; };

__global__ void k_prep(WPtrs wp, _Float16* __restrict__ ws) {
    int b = blockIdx.x;
    const float* src; int K, N, Np, Kp, off;
    if (b == 0)       { src = wp.p[0];  K = 3;   N = 128; Np = 128; Kp = 32;  off = 0; }
    else if (b == 1)  { src = wp.p[1];  K = 128; N = 128; Np = 128; Kp = 128; off = 4096; }
    else if (b == 2)  { src = wp.p[2];  K = 128; N = 32;  Np = 32;  Kp = 128; off = 20480; }
    else if (b == 3)  { src = wp.p[3];  K = 3;   N = 128; Np = 128; Kp = 32;  off = 24576; }
    else if (b == 4)  { src = wp.p[4];  K = 128; N = 128; Np = 128; Kp = 128; off = 28672; }
    else if (b == 5)  { src = wp.p[5];  K = 128; N = 32;  Np = 32;  Kp = 128; off = 45056; }
    else if (b <= 9)  { int t = b - 6;  src = wp.p[6] + t * 12288;  K = 96;  N = 128; Np = 128; Kp = 96;  off = 49152 + t * 32768; }
    else if (b <= 13) { int t = b - 10; src = wp.p[7] + t * 16384;  K = 128; N = 128; Np = 128; Kp = 128; off = 61440 + t * 32768; }
    else if (b <= 17) { int t = b - 14; src = wp.p[8] + t * 4096;   K = 128; N = 32;  Np = 32;  Kp = 128; off = 77824 + t * 32768; }
    else if (b <= 21) { int t = b - 18; src = wp.p[9] + t * 8192;   K = 64;  N = 128; Np = 128; Kp = 64;  off = 180224 + t * 28672; }
    else if (b <= 25) { int t = b - 22; src = wp.p[10] + t * 16384; K = 128; N = 128; Np = 128; Kp = 128; off = 188416 + t * 28672; }
    else if (b <= 29) { int t = b - 26; src = wp.p[11] + t * 4096;  K = 128; N = 32;  Np = 32;  Kp = 128; off = 204800 + t * 28672; }
    else if (b == 30) { src = wp.p[12]; K = 32;  N = 128; Np = 128; Kp = 32;  off = 294912; }
    else if (b == 31) { src = wp.p[13]; K = 128; N = 128; Np = 128; Kp = 128; off = 299008; }
    else              { src = wp.p[14]; K = 128; N = 1;   Np = 16;  Kp = 128; off = 315392; }
    int total = Np * Kp;
    for (int i = threadIdx.x; i < total; i += 256) {
        int n = i / Kp, k = i - n * Kp;
        float v = (k < K && n < N) ? src[k * N + n] : 0.f;
        ws[off + i] = (_Float16)v;
    }
}

// ---------------- CSR build: histogram -> scan -> scatter (u32 atomics only) -----
__global__ void k_zero(unsigned* __restrict__ p, int n) {
    int i = blockIdx.x * 256 + threadIdx.x;
    if (i < n) p[i] = 0u;
}
__global__ void k_hist(const int* __restrict__ gi, unsigned* __restrict__ cnt) {
    int e = blockIdx.x * 256 + threadIdx.x;
    if (e < 512000) atomicAdd(&cnt[gi[2 * e + 1]], 1u);
}
// one block, 1024 threads: exclusive scan of cnt[0..32000) via Kogge-Stone.
__global__ __launch_bounds__(1024) void k_scan(
    const unsigned* __restrict__ cnt, unsigned* __restrict__ rowptr,
    unsigned* __restrict__ cursor) {
    __shared__ unsigned s[1024];
    int t = threadIdx.x;
    unsigned loc[32];
    unsigned sum = 0;
#pragma unroll
    for (int i = 0; i < 32; ++i) {
        int idx = t * 32 + i;
        unsigned v = (idx < 32000) ? cnt[idx] : 0u;
        loc[i] = v; sum += v;
    }
    s[t] = sum;
    __syncthreads();
#pragma unroll
    for (int d = 1; d < 1024; d <<= 1) {
        unsigned x = (t >= d) ? s[t - d] : 0u;
        __syncthreads();
        s[t] += x;
        __syncthreads();
    }
    if (t == 1023) rowptr[32000] = s[1023];
    unsigned off = (t == 0) ? 0u : s[t - 1];
#pragma unroll
    for (int i = 0; i < 32; ++i) {
        int idx = t * 32 + i;
        if (idx < 32000) { rowptr[idx] = off; cursor[idx] = off; off += loc[i]; }
    }
}
__global__ void k_scatter(const int* __restrict__ gi, unsigned* __restrict__ cursor,
                          unsigned* __restrict__ iperm, int2* __restrict__ sr) {
    int e = blockIdx.x * 256 + threadIdx.x;
    if (e < 512000) {
        int s = gi[2 * e], r = gi[2 * e + 1];
        unsigned pos = atomicAdd(&cursor[r], 1u);
        iperm[pos] = (unsigned)e;
        sr[pos] = make_int2(s, r);
    }
}

// ---------------- encoder: fp32 [M][3] -> MLP -> f16 out rows (64-row tiles) -----
// R10 structure (in-loop gather), untouched for clean attribution.
__global__ __launch_bounds__(256, 3) void k_enc(
    const float* __restrict__ in, _Float16* __restrict__ out,
    const _Float16* __restrict__ w0t, const _Float16* __restrict__ w1t,
    const _Float16* __restrict__ w2t, int NT, const unsigned* __restrict__ iperm) {
    __shared__ __align__(16) _Float16 Xp[64 * 40];
    __shared__ __align__(16) _Float16 H0[64 * 136];
    __shared__ __align__(16) _Float16 H1[64 * 136];
    const int tid = threadIdx.x, w = tid >> 6, lane = tid & 63;
    const int q = lane >> 4, l16 = lane & 15;
    f16x8 w0f[1][2], w1f[4][2], w2f[4];
    load_wf2<1>(w0t, 32, w * 32, l16, q, w0f);
    load_wf2<4>(w1t, 128, w * 32, l16, q, w1f);
    {
        int n2 = (w & 1) * 16 + l16;
#pragma unroll
        for (int ks = 0; ks < 4; ++ks)
            w2f[ks] = *(const f16x8*)(w2t + n2 * 128 + ks * 32 + q * 8);
    }
    for (int c = tid; c < 2560; c += 256) Xp[c] = (_Float16)0.f;
    BAR();

    const int g = gridDim.x;
    const int dr = tid / 3, dc = tid - dr * 3;  // valid when tid<192
    const int orow = (w >> 1) * 16 + l16, ocol = (w & 1) * 16 + q * 4;
    int t = blockIdx.x;

    while (true) {
        if (tid < 192) {
            unsigned e = iperm ? iperm[t * 64 + dr] : (unsigned)(t * 64 + dr);
            Xp[dr * 40 + dc] = (_Float16)in[e * 3 + dc];
        }
        BAR();
        l0<1, 4>(w0f, Xp, 40, H0, l16, w * 32, 0, q);
        l1<4>(w1f, H0, H1, l16, w * 32, 0, q);
#pragma unroll
        for (int gg = 0; gg < 2; ++gg) {
            f32x4 o = l2g(w2f, H1, l16, w, q, gg);
            f16x4 ov;
#pragma unroll
            for (int i = 0; i < 4; ++i) ov[i] = (_Float16)o[i];
            *(f16x4*)(out + (t * 64 + gg * 32 + orow) * 32 + ocol) = ov;
        }
        t += g;
        if (t >= NT) break;
    }
}

// ---------------- edge update: [edge|node_s|node_r](96) -> MLP -> +res -----------
// R17: 8 waves (512 thr), same 64-row tile, same total work. Wave w: feature
// slice (w&3)*32 for l0/l1, row half (w>>2) (mb = 2*(w>>2)); l2: (w>>1) row
// group x (w&1) col half, single MFMA group. Staging: 768 chunks, thread tid
// takes chunk tid (all) + chunk tid+512 (waves 0-3 only; wave-uniform branch).
// R10 barrier structure (3/tile), padded Xe stride 104, per-thread loads.
__global__ __launch_bounds__(512, 6) void k_edge(
    const _Float16* __restrict__ node, _Float16* __restrict__ edgeP,
    const int2* __restrict__ sr,
    const _Float16* __restrict__ w0t, const _Float16* __restrict__ w1t,
    const _Float16* __restrict__ w2t) {
    __shared__ __align__(16) _Float16 Xe[64 * 104];
    __shared__ __align__(16) _Float16 H0[64 * 136];
    __shared__ __align__(16) _Float16 H1[64 * 136];
    const int tid = threadIdx.x, w = tid >> 6, lane = tid & 63;
    const int q = lane >> 4, l16 = lane & 15;
    const int w4 = w & 3, mb = (w >> 2) * 2;
    f16x8 w0f[3][2], w1f[4][2], w2f[4];
    load_wf2<3>(w0t, 96, w4 * 32, l16, q, w0f);
    load_wf2<4>(w1t, 128, w4 * 32, l16, q, w1f);
    {
        int n2 = (w & 1) * 16 + l16;
#pragma unroll
        for (int ks = 0; ks < 4; ++ks)
            w2f[ks] = *(const f16x8*)(w2t + n2 * 128 + ks * 32 + q * 8);
    }
    // staging chunks: c0 = tid (0..511), c1 = tid+512 (waves 0-3 only)
    const int cr0 = tid / 12, cs0 = tid - cr0 * 12;
    const int c1 = tid + 512;
    const int cr1 = c1 / 12, cs1 = c1 - cr1 * 12;
    const bool has2 = (tid < 256);
    const int orow = (w >> 1) * 16 + l16, ocol = (w & 1) * 16 + q * 4;

    const int NT = 8000, g = gridDim.x;
    int t = blockIdx.x;
    int2 srv0 = sr[t * 64 + cr0];
    int2 srv1 = make_int2(0, 0);
    if (has2) srv1 = sr[t * 64 + cr1];

    while (true) {
        int tn = t + g; if (tn >= NT) tn = t;
        // stage tile t
        int4 v0, v1;
        {
            int s = cs0;
            const _Float16* src = (s < 4) ? edgeP + (t * 64 + cr0) * 32 + s * 8
                               : (s < 8) ? node + srv0.x * 32 + (s - 4) * 8
                                         : node + srv0.y * 32 + (s - 8) * 8;
            v0 = *(const int4*)src;
        }
        if (has2) {
            int s = cs1;
            const _Float16* src = (s < 4) ? edgeP + (t * 64 + cr1) * 32 + s * 8
                               : (s < 8) ? node + srv1.x * 32 + (s - 4) * 8
                                         : node + srv1.y * 32 + (s - 8) * 8;
            v1 = *(const int4*)src;
        }
        int2 srn0 = sr[tn * 64 + cr0];
        int2 srn1 = make_int2(0, 0);
        if (has2) srn1 = sr[tn * 64 + cr1];
        *(int4*)(Xe + cr0 * 104 + cs0 * 8) = v0;
        if (has2) *(int4*)(Xe + cr1 * 104 + cs1 * 8) = v1;
        BAR();  // 1: Xe visible
        // old edge latent (cols 0..31) at this wave's l2 output coords
        f16x4 oldv = *(const f16x4*)(Xe + orow * 104 + ocol);

        l0<3, 2>(w0f, Xe, 104, H0, l16, w4 * 32, mb, q);  // BAR 2 inside
        l1<2>(w1f, H0, H1, l16, w4 * 32, mb, q);          // BAR 3 inside
        f32x4 o = l2g(w2f, H1, l16, w, q, 0);
        f16x4 nv;
#pragma unroll
        for (int i = 0; i < 4; ++i) nv[i] = (_Float16)(o[i] + (float)oldv[i]);
        *(f16x4*)(edgeP + (t * 64 + orow) * 32 + ocol) = nv;

        if (tn == t) break;
        t = tn;
        srv0 = srn0; srv1 = srn1;
    }
}

// ---------------- node update: [node|csr_sum(edgeP)](64) -> MLP -> +res ----------
// One 32-row tile per block (proven variant). Aggregation = contiguous fp32
// segment sum over f16 rows. Old node latent read from LDS (Xn cols 0..31).
__global__ __launch_bounds__(256, 3) void k_node(
    _Float16* __restrict__ node, const _Float16* __restrict__ edgeP,
    const unsigned* __restrict__ rowptr,
    const _Float16* __restrict__ w0t, const _Float16* __restrict__ w1t,
    const _Float16* __restrict__ w2t) {
    __shared__ __align__(16) _Float16 Xn[32 * 72];
    __shared__ __align__(16) _Float16 H0[32 * 136];
    __shared__ __align__(16) _Float16 H1[32 * 136];
    const int tid = threadIdx.x, w = tid >> 6, lane = tid & 63;
    const int q = lane >> 4, l16 = lane & 15;
    f16x8 w0f[2][2], w1f[4][2], w2f[4];
    load_wf2<2>(w0t, 64, w * 32, l16, q, w0f);
    load_wf2<4>(w1t, 128, w * 32, l16, q, w1f);
    {
        int n2 = (w & 1) * 16 + l16;
#pragma unroll
        for (int ks = 0; ks < 4; ++ks)
            w2f[ks] = *(const f16x8*)(w2t + n2 * 128 + ks * 32 + q * 8);
    }
    const int t = blockIdx.x;
    const int orow = (w >> 1) * 16 + l16, ocol = (w & 1) * 16 + q * 4;
    // 8 chunks/row (16 B each): cs<4 node copy, cs>=4 segment-sum of edgeP chunk
    {
        int cr = tid >> 3, cs = tid & 7;
        int r = t * 32 + cr;
        if (cs < 4) {
            *(int4*)(Xn + cr * 72 + cs * 8) = *(const int4*)(node + r * 32 + cs * 8);
        } else {
            unsigned b = rowptr[r], e = rowptr[r + 1];
            const _Float16* base = edgeP + (cs - 4) * 8;
            float a0[8], a1[8];
#pragma unroll
            for (int i = 0; i < 8; ++i) { a0[i] = 0.f; a1[i] = 0.f; }
            unsigned p = b;
            for (; p + 2 <= e; p += 2) {
                f16x8 x0 = *(const f16x8*)(base + (p + 0) * 32);
                f16x8 x1 = *(const f16x8*)(base + (p + 1) * 32);
#pragma unroll
                for (int i = 0; i < 8; ++i) { a0[i] += (float)x0[i]; a1[i] += (float)x1[i]; }
            }
            if (p < e) {
                f16x8 x0 = *(const f16x8*)(base + p * 32);
#pragma unroll
                for (int i = 0; i < 8; ++i) a0[i] += (float)x0[i];
            }
            f16x8 h;
#pragma unroll
            for (int i = 0; i < 8; ++i) h[i] = (_Float16)(a0[i] + a1[i]);
            *(f16x8*)(Xn + cr * 72 + cs * 8) = h;
        }
    }
    BAR();
    f16x4 oldv = *(const f16x4*)(Xn + orow * 72 + ocol);
    l0<2, 2>(w0f, Xn, 72, H0, l16, w * 32, 0, q);
    l1<2>(w1f, H0, H1, l16, w * 32, 0, q);
    f32x4 o = l2g(w2f, H1, l16, w, q, 0);
    f16x4 nv;
#pragma unroll
    for (int i = 0; i < 4; ++i) nv[i] = (_Float16)(o[i] + (float)oldv[i]);
    *(f16x4*)(node + (t * 32 + orow) * 32 + ocol) = nv;
}

// ---------------- decoder: node(32) -> MLP(32->128->128->1) -> fp32 out ----------
__global__ __launch_bounds__(256, 3) void k_dec(
    const _Float16* __restrict__ node,
    const _Float16* __restrict__ w0t, const _Float16* __restrict__ w1t,
    const _Float16* __restrict__ w2t, float* __restrict__ out) {
    __shared__ __align__(16) _Float16 Xd[64 * 40];
    __shared__ __align__(16) _Float16 H0[64 * 136];
    __shared__ __align__(16) _Float16 H1[64 * 136];
    const int tid = threadIdx.x, w = tid >> 6, lane = tid & 63;
    const int q = lane >> 4, l16 = lane & 15;
    f16x8 w0f[1][2], w1f[4][2], w2f[4];
    load_wf2<1>(w0t, 32, w * 32, l16, q, w0f);
    load_wf2<4>(w1t, 128, w * 32, l16, q, w1f);
    {
        int n2 = l16;  // padded W2^T is [16][128]; all waves load tile 0
#pragma unroll
        for (int ks = 0; ks < 4; ++ks)
            w2f[ks] = *(const f16x8*)(w2t + n2 * 128 + ks * 32 + q * 8);
    }
    const int t = blockIdx.x;
    {
        int cr = tid >> 2, cs = tid & 3;
        *(int4*)(Xd + cr * 40 + cs * 8) = *(const int4*)(node + (t * 64 + cr) * 32 + cs * 8);
    }
    BAR();
    l0<1, 4>(w0f, Xd, 40, H0, l16, w * 32, 0, q);
    l1<4>(w1f, H0, H1, l16, w * 32, 0, q);
#pragma unroll
    for (int gg = 0; gg < 2; ++gg) {
        f32x4 o = l2g(w2f, H1, l16, w, q, gg);
        // only col 0 is real: waves with (w&1)==0, lanes q==0, reg 0
        if ((w & 1) == 0 && q == 0) out[t * 64 + gg * 32 + (w >> 1) * 16 + l16] = o[0];
    }
}

extern "C" void kernel_launch(void* const* d_in, const int* in_sizes, int n_in,
                              void* d_out, int out_size, void* d_ws, size_t ws_size,
                              hipStream_t stream) {
    const float* input_node = (const float*)d_in[0];
    const float* input_edge = (const float*)d_in[1];
    const int* gi = (const int*)d_in[2];

    _Float16* ws = (_Float16*)d_ws;
    // ws layout (bytes):
    //   weights f16:         [0,          634,880)
    //   node  f16 32000x32:  [655,360,    2,703,360)
    //   edgeP f16 512000x32: [2,703,360,  35,471,360)   (receiver-sorted rows)
    //   rowptr u32[32001]:   [35,471,360, 35,599,364)
    //   cursor u32[32000]:   [35,599,616, 35,727,616)
    //   iperm  u32[512000]:  [35,727,616, 37,775,616)
    //   sr   int2[512000]:   [37,775,616, 41,871,616)
    _Float16* node = (_Float16*)((char*)d_ws + 655360);
    _Float16* edgeP = (_Float16*)((char*)d_ws + 2703360);
    unsigned* rowptr = (unsigned*)((char*)d_ws + 35471360);
    unsigned* cursor = (unsigned*)((char*)d_ws + 35599616);
    unsigned* iperm = (unsigned*)((char*)d_ws + 35727616);
    int2* sr = (int2*)((char*)d_ws + 37775616);

    WPtrs wp;
    for (int i = 0; i < 15; ++i) wp.p[i] = (const float*)d_in[3 + i];

    k_prep<<<33, 256, 0, stream>>>(wp, ws);

    // CSR build (u32 atomics only)
    k_zero<<<125, 256, 0, stream>>>(cursor, 32000);
    k_hist<<<2000, 256, 0, stream>>>(gi, cursor);
    k_scan<<<1, 1024, 0, stream>>>(cursor, rowptr, cursor);
    k_scatter<<<2000, 256, 0, stream>>>(gi, cursor, iperm, sr);

    k_enc<<<500, 256, 0, stream>>>(input_node, node, ws + 0, ws + 4096, ws + 20480,
                                   500, nullptr);
    k_enc<<<768, 256, 0, stream>>>(input_edge, edgeP, ws + 24576, ws + 28672,
                                   ws + 45056, 8000, iperm);

    for (int t = 0; t < 4; ++t) {
        k_edge<<<768, 512, 0, stream>>>(node, edgeP, sr,
                                        ws + 49152 + t * 32768,
                                        ws + 61440 + t * 32768,
                                        ws + 77824 + t * 32768);
        k_node<<<1000, 256, 0, stream>>>(node, edgeP, rowptr,
                                         ws + 180224 + t * 28672,
                                         ws + 188416 + t * 28672,
                                         ws + 204800 + t * 28672);
    }
    k_dec<<<500, 256, 0, stream>>>(node, ws + 294912, ws + 299008, ws + 315392,
                                   (float*)d_out);
}

// Round 7
// 841.730 us; speedup vs baseline: 1.0707x; 1.0707x over previous
//
#include <hip/hip_runtime.h>

typedef __attribute__((ext_vector_type(8))) _Float16 f16x8;
typedef __attribute__((ext_vector_type(4))) _Float16 f16x4;
typedef __attribute__((ext_vector_type(4))) float f32x4;

#define DI __device__ __forceinline__
// Raw barrier: LDS-drain only (lgkmcnt). Avoids the compiler's vmcnt(0) drain.
#define BAR() asm volatile("s_waitcnt lgkmcnt(0)\n\ts_barrier" ::: "memory")

DI f32x4 mfma16(f16x8 a, f16x8 b, f32x4 c) {
    return __builtin_amdgcn_mfma_f32_16x16x32_f16(a, b, c, 0, 0, 0);
}

// Wave-mapping (4-wave kernels): wave w owns features [w*32, w*32+32) for layers
// 0/1; layer 2: wave w -> rows (w>>1)*16 (+32*g), cols (w&1)*16.
// PROVEN STATE (R10, 504 us): lb(256,3), 64-row k_edge/k_enc/k_dec, 32-row k_node.
// R11 lesson: lb(256,4) caps regs at 128 -> weights evicted -> regression.
// R12 lesson: 64-row k_node diverged intermittently under graph replay -> revert.
// R13/R15 lesson: register-held gather prefetch spills regardless of waves_per_eu.
// R14 lesson: LDS shrink for 4 blocks/CU: achieved occupancy FELL; extra BAR -5%.
// R16 lesson: DMA prefetch clean but neutral -> staging latency not critical path.
// R17 lesson: 8-wave TLP forces weight eviction (VGPR 40, FETCH 402MB, MFMA 8.8%).
//   Weight-resident design pins 3 waves/SIMD. 51.5us k_edge = structural plateau.
// R18 (this round): back to exact R10 structure + persistent-block dynamic tile
//   stealing (atomic counter) in k_edge/k_enc to kill the ceil(8000/768) tail
//   (~9% of wall). tid0 draws next tile into LDS slot sT at loop top; published
//   by existing BAR1; consumed after it. Counters zeroed by k_prep block 33.

template <int NK>
DI void load_wf2(const _Float16* __restrict__ wt, int Kp, int nbase, int l16, int q,
                 f16x8 f[NK][2]) {
#pragma unroll
    for (int nt = 0; nt < 2; ++nt) {
        int n = nbase + nt * 16 + l16;
#pragma unroll
        for (int ks = 0; ks < NK; ++ks)
            f[ks][nt] = *(const f16x8*)(wt + n * Kp + ks * 32 + q * 8);
    }
}

// Layer 0 over MH 16-row groups starting at row-group mb: H0' = relu(W0^T X^T).
// nb = feature base (halves). f16 out to H0 (stride 136). BAR.
template <int NK0, int MH>
DI void l0(const f16x8 (*w0f)[2], const _Float16* __restrict__ X, int xstride,
           _Float16* __restrict__ H0, int l16, int nb, int mb, int q) {
    const f32x4 zero = {0.f, 0.f, 0.f, 0.f};
    f32x4 acc[2][MH];
#pragma unroll
    for (int nt = 0; nt < 2; ++nt)
#pragma unroll
        for (int mt = 0; mt < MH; ++mt) acc[nt][mt] = zero;
#pragma unroll
    for (int ks = 0; ks < NK0; ++ks) {
        f16x8 x[MH];
#pragma unroll
        for (int mt = 0; mt < MH; ++mt)
            x[mt] = *(const f16x8*)(X + ((mb + mt) * 16 + l16) * xstride + ks * 32 + q * 8);
#pragma unroll
        for (int nt = 0; nt < 2; ++nt)
#pragma unroll
            for (int mt = 0; mt < MH; ++mt)
                acc[nt][mt] = mfma16(w0f[ks][nt], x[mt], acc[nt][mt]);
    }
#pragma unroll
    for (int mt = 0; mt < MH; ++mt)
#pragma unroll
        for (int nt = 0; nt < 2; ++nt) {
            f16x4 h;
#pragma unroll
            for (int i = 0; i < 4; ++i) h[i] = (_Float16)fmaxf(acc[nt][mt][i], 0.f);
            *(f16x4*)(H0 + ((mb + mt) * 16 + l16) * 136 + nb + nt * 16 + q * 4) = h;
        }
    BAR();
}

// Layer 1: H1' = relu(W1^T H0^T) over the same row groups. BAR.
template <int MH>
DI void l1(const f16x8 (*w1f)[2], const _Float16* __restrict__ H0,
           _Float16* __restrict__ H1, int l16, int nb, int mb, int q) {
    const f32x4 zero = {0.f, 0.f, 0.f, 0.f};
    f32x4 a1[2][MH];
#pragma unroll
    for (int nt = 0; nt < 2; ++nt)
#pragma unroll
        for (int mt = 0; mt < MH; ++mt) a1[nt][mt] = zero;
#pragma unroll
    for (int ks = 0; ks < 4; ++ks) {
        f16x8 x[MH];
#pragma unroll
        for (int mt = 0; mt < MH; ++mt)
            x[mt] = *(const f16x8*)(H0 + ((mb + mt) * 16 + l16) * 136 + ks * 32 + q * 8);
#pragma unroll
        for (int nt = 0; nt < 2; ++nt)
#pragma unroll
            for (int mt = 0; mt < MH; ++mt)
                a1[nt][mt] = mfma16(w1f[ks][nt], x[mt], a1[nt][mt]);
    }
#pragma unroll
    for (int mt = 0; mt < MH; ++mt)
#pragma unroll
        for (int nt = 0; nt < 2; ++nt) {
            f16x4 h;
#pragma unroll
            for (int i = 0; i < 4; ++i) h[i] = (_Float16)fmaxf(a1[nt][mt][i], 0.f);
            *(f16x4*)(H1 + ((mb + mt) * 16 + l16) * 136 + nb + nt * 16 + q * 4) = h;
        }
    BAR();
}

// Layer 2, row group g: rows (w>>1)*16 + l16 + 32*g, cols (w&1)*16 + q*4 + i.
DI f32x4 l2g(const f16x8* w2f, const _Float16* __restrict__ H1, int l16, int w,
             int q, int g) {
    int m = (w >> 1) * 16 + l16 + 32 * g;
    f32x4 acc = {0.f, 0.f, 0.f, 0.f};
#pragma unroll
    for (int ks = 0; ks < 4; ++ks) {
        f16x8 x = *(const f16x8*)(H1 + m * 136 + ks * 32 + q * 8);
        acc = mfma16(w2f[ks], x, acc);
    }
    return acc;
}

// ---------------- weight prep: fp32 [K][N] -> f16 W^T [Np][Kp] (zero padded) ----
// Block 33 zeroes the 6 dynamic-tile counters (ws bytes 35,599,400..424).
struct WPtrs { const float* p[15]; };

__global__ void k_prep(WPtrs wp, _Float16* __restrict__ ws) {
    int b = blockIdx.x;
    if (b == 33) {
        unsigned* ctr = (unsigned*)((char*)ws + 35599400);
        if (threadIdx.x < 6) ctr[threadIdx.x] = 0u;
        return;
    }
    const float* src; int K, N, Np, Kp, off;
    if (b == 0)       { src = wp.p[0];  K = 3;   N = 128; Np = 128; Kp = 32;  off = 0; }
    else if (b == 1)  { src = wp.p[1];  K = 128; N = 128; Np = 128; Kp = 128; off = 4096; }
    else if (b == 2)  { src = wp.p[2];  K = 128; N = 32;  Np = 32;  Kp = 128; off = 20480; }
    else if (b == 3)  { src = wp.p[3];  K = 3;   N = 128; Np = 128; Kp = 32;  off = 24576; }
    else if (b == 4)  { src = wp.p[4];  K = 128; N = 128; Np = 128; Kp = 128; off = 28672; }
    else if (b == 5)  { src = wp.p[5];  K = 128; N = 32;  Np = 32;  Kp = 128; off = 45056; }
    else if (b <= 9)  { int t = b - 6;  src = wp.p[6] + t * 12288;  K = 96;  N = 128; Np = 128; Kp = 96;  off = 49152 + t * 32768; }
    else if (b <= 13) { int t = b - 10; src = wp.p[7] + t * 16384;  K = 128; N = 128; Np = 128; Kp = 128; off = 61440 + t * 32768; }
    else if (b <= 17) { int t = b - 14; src = wp.p[8] + t * 4096;   K = 128; N = 32;  Np = 32;  Kp = 128; off = 77824 + t * 32768; }
    else if (b <= 21) { int t = b - 18; src = wp.p[9] + t * 8192;   K = 64;  N = 128; Np = 128; Kp = 64;  off = 180224 + t * 28672; }
    else if (b <= 25) { int t = b - 22; src = wp.p[10] + t * 16384; K = 128; N = 128; Np = 128; Kp = 128; off = 188416 + t * 28672; }
    else if (b <= 29) { int t = b - 26; src = wp.p[11] + t * 4096;  K = 128; N = 32;  Np = 32;  Kp = 128; off = 204800 + t * 28672; }
    else if (b == 30) { src = wp.p[12]; K = 32;  N = 128; Np = 128; Kp = 32;  off = 294912; }
    else if (b == 31) { src = wp.p[13]; K = 128; N = 128; Np = 128; Kp = 128; off = 299008; }
    else              { src = wp.p[14]; K = 128; N = 1;   Np = 16;  Kp = 128; off = 315392; }
    int total = Np * Kp;
    for (int i = threadIdx.x; i < total; i += 256) {
        int n = i / Kp, k = i - n * Kp;
        float v = (k < K && n < N) ? src[k * N + n] : 0.f;
        ws[off + i] = (_Float16)v;
    }
}

// ---------------- CSR build: histogram -> scan -> scatter (u32 atomics only) -----
__global__ void k_zero(unsigned* __restrict__ p, int n) {
    int i = blockIdx.x * 256 + threadIdx.x;
    if (i < n) p[i] = 0u;
}
__global__ void k_hist(const int* __restrict__ gi, unsigned* __restrict__ cnt) {
    int e = blockIdx.x * 256 + threadIdx.x;
    if (e < 512000) atomicAdd(&cnt[gi[2 * e + 1]], 1u);
}
// one block, 1024 threads: exclusive scan of cnt[0..32000) via Kogge-Stone.
__global__ __launch_bounds__(1024) void k_scan(
    const unsigned* __restrict__ cnt, unsigned* __restrict__ rowptr,
    unsigned* __restrict__ cursor) {
    __shared__ unsigned s[1024];
    int t = threadIdx.x;
    unsigned loc[32];
    unsigned sum = 0;
#pragma unroll
    for (int i = 0; i < 32; ++i) {
        int idx = t * 32 + i;
        unsigned v = (idx < 32000) ? cnt[idx] : 0u;
        loc[i] = v; sum += v;
    }
    s[t] = sum;
    __syncthreads();
#pragma unroll
    for (int d = 1; d < 1024; d <<= 1) {
        unsigned x = (t >= d) ? s[t - d] : 0u;
        __syncthreads();
        s[t] += x;
        __syncthreads();
    }
    if (t == 1023) rowptr[32000] = s[1023];
    unsigned off = (t == 0) ? 0u : s[t - 1];
#pragma unroll
    for (int i = 0; i < 32; ++i) {
        int idx = t * 32 + i;
        if (idx < 32000) { rowptr[idx] = off; cursor[idx] = off; off += loc[i]; }
    }
}
__global__ void k_scatter(const int* __restrict__ gi, unsigned* __restrict__ cursor,
                          unsigned* __restrict__ iperm, int2* __restrict__ sr) {
    int e = blockIdx.x * 256 + threadIdx.x;
    if (e < 512000) {
        int s = gi[2 * e], r = gi[2 * e + 1];
        unsigned pos = atomicAdd(&cursor[r], 1u);
        iperm[pos] = (unsigned)e;
        sr[pos] = make_int2(s, r);
    }
}

// ---------------- encoder: fp32 [M][3] -> MLP -> f16 out rows (64-row tiles) -----
// R18: dynamic tile stealing. tid0 draws next tile at loop top; published by the
// staging BAR; consumed after. Exit decision block-uniform (sT).
__global__ __launch_bounds__(256, 3) void k_enc(
    const float* __restrict__ in, _Float16* __restrict__ out,
    const _Float16* __restrict__ w0t, const _Float16* __restrict__ w1t,
    const _Float16* __restrict__ w2t, int NT, const unsigned* __restrict__ iperm,
    unsigned* __restrict__ ctr) {
    __shared__ __align__(16) _Float16 Xp[64 * 40];
    __shared__ __align__(16) _Float16 H0[64 * 136];
    __shared__ __align__(16) _Float16 H1[64 * 136];
    __shared__ unsigned sT;
    const int tid = threadIdx.x, w = tid >> 6, lane = tid & 63;
    const int q = lane >> 4, l16 = lane & 15;
    f16x8 w0f[1][2], w1f[4][2], w2f[4];
    load_wf2<1>(w0t, 32, w * 32, l16, q, w0f);
    load_wf2<4>(w1t, 128, w * 32, l16, q, w1f);
    {
        int n2 = (w & 1) * 16 + l16;
#pragma unroll
        for (int ks = 0; ks < 4; ++ks)
            w2f[ks] = *(const f16x8*)(w2t + n2 * 128 + ks * 32 + q * 8);
    }
    for (int c = tid; c < 2560; c += 256) Xp[c] = (_Float16)0.f;
    if (tid == 0) sT = atomicAdd(ctr, 1u);
    BAR();
    int t = (int)sT;
    if (t >= NT) return;

    const int dr = tid / 3, dc = tid - dr * 3;  // valid when tid<192
    const int orow = (w >> 1) * 16 + l16, ocol = (w & 1) * 16 + q * 4;

    while (true) {
        if (tid == 0) sT = atomicAdd(ctr, 1u);
        if (tid < 192) {
            unsigned e = iperm ? iperm[t * 64 + dr] : (unsigned)(t * 64 + dr);
            Xp[dr * 40 + dc] = (_Float16)in[e * 3 + dc];
        }
        BAR();  // publishes Xp and sT
        int tn = (int)sT;
        bool done = (tn >= NT);
        l0<1, 4>(w0f, Xp, 40, H0, l16, w * 32, 0, q);
        l1<4>(w1f, H0, H1, l16, w * 32, 0, q);
#pragma unroll
        for (int gg = 0; gg < 2; ++gg) {
            f32x4 o = l2g(w2f, H1, l16, w, q, gg);
            f16x4 ov;
#pragma unroll
            for (int i = 0; i < 4; ++i) ov[i] = (_Float16)o[i];
            *(f16x4*)(out + (t * 64 + gg * 32 + orow) * 32 + ocol) = ov;
        }
        if (done) break;
        t = tn;
    }
}

// ---------------- edge update: [edge|node_s|node_r](96) -> MLP -> +res -----------
// Exact R10 body (proven 51.5us) + dynamic tile stealing. tid0 draws tile t+1 at
// loop top into sT; BAR1 publishes it; srn loads (for t+1) issue after BAR1 and
// hide under l0/l1. Single sT slot safe: reads happen right after BAR1, next
// write is after BAR2+BAR3.
__global__ __launch_bounds__(256, 3) void k_edge(
    const _Float16* __restrict__ node, _Float16* __restrict__ edgeP,
    const int2* __restrict__ sr,
    const _Float16* __restrict__ w0t, const _Float16* __restrict__ w1t,
    const _Float16* __restrict__ w2t, unsigned* __restrict__ ctr) {
    __shared__ __align__(16) _Float16 Xe[64 * 104];
    __shared__ __align__(16) _Float16 H0[64 * 136];
    __shared__ __align__(16) _Float16 H1[64 * 136];
    __shared__ unsigned sT;
    const int tid = threadIdx.x, w = tid >> 6, lane = tid & 63;
    const int q = lane >> 4, l16 = lane & 15;
    f16x8 w0f[3][2], w1f[4][2], w2f[4];
    load_wf2<3>(w0t, 96, w * 32, l16, q, w0f);
    load_wf2<4>(w1t, 128, w * 32, l16, q, w1f);
    {
        int n2 = (w & 1) * 16 + l16;
#pragma unroll
        for (int ks = 0; ks < 4; ++ks)
            w2f[ks] = *(const f16x8*)(w2t + n2 * 128 + ks * 32 + q * 8);
    }
    int cr[3], cs[3];
#pragma unroll
    for (int j = 0; j < 3; ++j) {
        int c = tid + 256 * j;
        cr[j] = c / 12; cs[j] = c - cr[j] * 12;
    }
    const int orow = (w >> 1) * 16 + l16, ocol = (w & 1) * 16 + q * 4;
    const int NT = 8000;

    if (tid == 0) sT = atomicAdd(ctr, 1u);
    BAR();
    int t = (int)sT;
    if (t >= NT) return;
    int2 srv[3];
#pragma unroll
    for (int j = 0; j < 3; ++j) srv[j] = sr[t * 64 + cr[j]];

    while (true) {
        if (tid == 0) sT = atomicAdd(ctr, 1u);
        // stage tile t (loads issue; Xe write waits on them via vmcnt)
        int4 v[3];
#pragma unroll
        for (int j = 0; j < 3; ++j) {
            int s = cs[j];
            const _Float16* src = (s < 4) ? edgeP + (t * 64 + cr[j]) * 32 + s * 8
                               : (s < 8) ? node + srv[j].x * 32 + (s - 4) * 8
                                         : node + srv[j].y * 32 + (s - 8) * 8;
            v[j] = *(const int4*)src;
        }
#pragma unroll
        for (int j = 0; j < 3; ++j)
            *(int4*)(Xe + cr[j] * 104 + cs[j] * 8) = v[j];
        BAR();  // 1: Xe + sT visible
        int tn = (int)sT;
        bool done = (tn >= NT);
        int ts = done ? t : tn;
        // old edge latent from LDS (cols 0..31 of the staged tile)
        f16x4 oldv[2];
#pragma unroll
        for (int gg = 0; gg < 2; ++gg)
            oldv[gg] = *(const f16x4*)(Xe + (gg * 32 + orow) * 104 + ocol);
        // next-tile sr; latency hides under l0+l1
        int2 srn[3];
#pragma unroll
        for (int j = 0; j < 3; ++j) srn[j] = sr[ts * 64 + cr[j]];

        l0<3, 4>(w0f, Xe, 104, H0, l16, w * 32, 0, q);  // BAR 2 inside
        l1<4>(w1f, H0, H1, l16, w * 32, 0, q);          // BAR 3 inside
#pragma unroll
        for (int gg = 0; gg < 2; ++gg) {
            f32x4 o = l2g(w2f, H1, l16, w, q, gg);
            f16x4 nv;
#pragma unroll
            for (int i = 0; i < 4; ++i) nv[i] = (_Float16)(o[i] + (float)oldv[gg][i]);
            *(f16x4*)(edgeP + (t * 64 + gg * 32 + orow) * 32 + ocol) = nv;
        }

        if (done) break;
        t = tn;
#pragma unroll
        for (int j = 0; j < 3; ++j) srv[j] = srn[j];
    }
}

// ---------------- node update: [node|csr_sum(edgeP)](64) -> MLP -> +res ----------
// One 32-row tile per block (proven variant, untouched).
__global__ __launch_bounds__(256, 3) void k_node(
    _Float16* __restrict__ node, const _Float16* __restrict__ edgeP,
    const unsigned* __restrict__ rowptr,
    const _Float16* __restrict__ w0t, const _Float16* __restrict__ w1t,
    const _Float16* __restrict__ w2t) {
    __shared__ __align__(16) _Float16 Xn[32 * 72];
    __shared__ __align__(16) _Float16 H0[32 * 136];
    __shared__ __align__(16) _Float16 H1[32 * 136];
    const int tid = threadIdx.x, w = tid >> 6, lane = tid & 63;
    const int q = lane >> 4, l16 = lane & 15;
    f16x8 w0f[2][2], w1f[4][2], w2f[4];
    load_wf2<2>(w0t, 64, w * 32, l16, q, w0f);
    load_wf2<4>(w1t, 128, w * 32, l16, q, w1f);
    {
        int n2 = (w & 1) * 16 + l16;
#pragma unroll
        for (int ks = 0; ks < 4; ++ks)
            w2f[ks] = *(const f16x8*)(w2t + n2 * 128 + ks * 32 + q * 8);
    }
    const int t = blockIdx.x;
    const int orow = (w >> 1) * 16 + l16, ocol = (w & 1) * 16 + q * 4;
    // 8 chunks/row (16 B each): cs<4 node copy, cs>=4 segment-sum of edgeP chunk
    {
        int cr = tid >> 3, cs = tid & 7;
        int r = t * 32 + cr;
        if (cs < 4) {
            *(int4*)(Xn + cr * 72 + cs * 8) = *(const int4*)(node + r * 32 + cs * 8);
        } else {
            unsigned b = rowptr[r], e = rowptr[r + 1];
            const _Float16* base = edgeP + (cs - 4) * 8;
            float a0[8], a1[8];
#pragma unroll
            for (int i = 0; i < 8; ++i) { a0[i] = 0.f; a1[i] = 0.f; }
            unsigned p = b;
            for (; p + 2 <= e; p += 2) {
                f16x8 x0 = *(const f16x8*)(base + (p + 0) * 32);
                f16x8 x1 = *(const f16x8*)(base + (p + 1) * 32);
#pragma unroll
                for (int i = 0; i < 8; ++i) { a0[i] += (float)x0[i]; a1[i] += (float)x1[i]; }
            }
            if (p < e) {
                f16x8 x0 = *(const f16x8*)(base + p * 32);
#pragma unroll
                for (int i = 0; i < 8; ++i) a0[i] += (float)x0[i];
            }
            f16x8 h;
#pragma unroll
            for (int i = 0; i < 8; ++i) h[i] = (_Float16)(a0[i] + a1[i]);
            *(f16x8*)(Xn + cr * 72 + cs * 8) = h;
        }
    }
    BAR();
    f16x4 oldv = *(const f16x4*)(Xn + orow * 72 + ocol);
    l0<2, 2>(w0f, Xn, 72, H0, l16, w * 32, 0, q);
    l1<2>(w1f, H0, H1, l16, w * 32, 0, q);
    f32x4 o = l2g(w2f, H1, l16, w, q, 0);
    f16x4 nv;
#pragma unroll
    for (int i = 0; i < 4; ++i) nv[i] = (_Float16)(o[i] + (float)oldv[i]);
    *(f16x4*)(node + (t * 32 + orow) * 32 + ocol) = nv;
}

// ---------------- decoder: node(32) -> MLP(32->128->128->1) -> fp32 out ----------
__global__ __launch_bounds__(256, 3) void k_dec(
    const _Float16* __restrict__ node,
    const _Float16* __restrict__ w0t, const _Float16* __restrict__ w1t,
    const _Float16* __restrict__ w2t, float* __restrict__ out) {
    __shared__ __align__(16) _Float16 Xd[64 * 40];
    __shared__ __align__(16) _Float16 H0[64 * 136];
    __shared__ __align__(16) _Float16 H1[64 * 136];
    const int tid = threadIdx.x, w = tid >> 6, lane = tid & 63;
    const int q = lane >> 4, l16 = lane & 15;
    f16x8 w0f[1][2], w1f[4][2], w2f[4];
    load_wf2<1>(w0t, 32, w * 32, l16, q, w0f);
    load_wf2<4>(w1t, 128, w * 32, l16, q, w1f);
    {
        int n2 = l16;  // padded W2^T is [16][128]; all waves load tile 0
#pragma unroll
        for (int ks = 0; ks < 4; ++ks)
            w2f[ks] = *(const f16x8*)(w2t + n2 * 128 + ks * 32 + q * 8);
    }
    const int t = blockIdx.x;
    {
        int cr = tid >> 2, cs = tid & 3;
        *(int4*)(Xd + cr * 40 + cs * 8) = *(const int4*)(node + (t * 64 + cr) * 32 + cs * 8);
    }
    BAR();
    l0<1, 4>(w0f, Xd, 40, H0, l16, w * 32, 0, q);
    l1<4>(w1f, H0, H1, l16, w * 32, 0, q);
#pragma unroll
    for (int gg = 0; gg < 2; ++gg) {
        f32x4 o = l2g(w2f, H1, l16, w, q, gg);
        // only col 0 is real: waves with (w&1)==0, lanes q==0, reg 0
        if ((w & 1) == 0 && q == 0) out[t * 64 + gg * 32 + (w >> 1) * 16 + l16] = o[0];
    }
}

extern "C" void kernel_launch(void* const* d_in, const int* in_sizes, int n_in,
                              void* d_out, int out_size, void* d_ws, size_t ws_size,
                              hipStream_t stream) {
    const float* input_node = (const float*)d_in[0];
    const float* input_edge = (const float*)d_in[1];
    const int* gi = (const int*)d_in[2];

    _Float16* ws = (_Float16*)d_ws;
    // ws layout (bytes):
    //   weights f16:         [0,          634,880)
    //   node  f16 32000x32:  [655,360,    2,703,360)
    //   edgeP f16 512000x32: [2,703,360,  35,471,360)   (receiver-sorted rows)
    //   rowptr u32[32001]:   [35,471,360, 35,599,364)
    //   ctr    u32[6]:       [35,599,400, 35,599,424)   (dynamic tile counters)
    //   cursor u32[32000]:   [35,599,616, 35,727,616)
    //   iperm  u32[512000]:  [35,727,616, 37,775,616)
    //   sr   int2[512000]:   [37,775,616, 41,871,616)
    _Float16* node = (_Float16*)((char*)d_ws + 655360);
    _Float16* edgeP = (_Float16*)((char*)d_ws + 2703360);
    unsigned* rowptr = (unsigned*)((char*)d_ws + 35471360);
    unsigned* ctr = (unsigned*)((char*)d_ws + 35599400);
    unsigned* cursor = (unsigned*)((char*)d_ws + 35599616);
    unsigned* iperm = (unsigned*)((char*)d_ws + 35727616);
    int2* sr = (int2*)((char*)d_ws + 37775616);

    WPtrs wp;
    for (int i = 0; i < 15; ++i) wp.p[i] = (const float*)d_in[3 + i];

    k_prep<<<34, 256, 0, stream>>>(wp, ws);

    // CSR build (u32 atomics only)
    k_zero<<<125, 256, 0, stream>>>(cursor, 32000);
    k_hist<<<2000, 256, 0, stream>>>(gi, cursor);
    k_scan<<<1, 1024, 0, stream>>>(cursor, rowptr, cursor);
    k_scatter<<<2000, 256, 0, stream>>>(gi, cursor, iperm, sr);

    k_enc<<<500, 256, 0, stream>>>(input_node, node, ws + 0, ws + 4096, ws + 20480,
                                   500, nullptr, ctr + 0);
    k_enc<<<768, 256, 0, stream>>>(input_edge, edgeP, ws + 24576, ws + 28672,
                                   ws + 45056, 8000, iperm, ctr + 1);

    for (int t = 0; t < 4; ++t) {
        k_edge<<<768, 256, 0, stream>>>(node, edgeP, sr,
                                        ws + 49152 + t * 32768,
                                        ws + 61440 + t * 32768,
                                        ws + 77824 + t * 32768, ctr + 2 + t);
        k_node<<<1000, 256, 0, stream>>>(node, edgeP, rowptr,
                                         ws + 180224 + t * 28672,
                                         ws + 188416 + t * 28672,
                                         ws + 204800 + t * 28672);
    }
    k_dec<<<500, 256, 0, stream>>>(node, ws + 294912, ws + 299008, ws + 315392,
                                   (float*)d_out);
}

// Round 8
// 491.710 us; speedup vs baseline: 1.8328x; 1.7118x over previous
//
#include <hip/hip_runtime.h>

typedef __attribute__((ext_vector_type(8))) _Float16 f16x8;
typedef __attribute__((ext_vector_type(4))) _Float16 f16x4;
typedef __attribute__((ext_vector_type(4))) float f32x4;

#define DI __device__ __forceinline__
// Raw barrier: LDS-drain only (lgkmcnt). Avoids the compiler's vmcnt(0) drain.
#define BAR() asm volatile("s_waitcnt lgkmcnt(0)\n\ts_barrier" ::: "memory")

DI f32x4 mfma16(f16x8 a, f16x8 b, f32x4 c) {
    return __builtin_amdgcn_mfma_f32_16x16x32_f16(a, b, c, 0, 0, 0);
}

// Wave-mapping (4-wave kernels): wave w owns features [w*32, w*32+32) for layers
// 0/1; layer 2: wave w -> rows (w>>1)*16 (+32*g), cols (w&1)*16.
// PROVEN STATE (R10, 502-504 us): lb(256,3), 64-row k_edge/k_enc/k_dec, 32-row
// k_node, blockIdx-strided persistent loops, grids 768.
// R11: lb(256,4) caps regs at 128 -> weights evicted -> regression.
// R12: 64-row k_node diverged intermittently under graph replay -> revert.
// R13/R15: register-held gather prefetch spills regardless of waves_per_eu.
// R14: LDS shrink for 4 blk/CU: achieved occupancy FELL; extra BAR -5%.
// R16: DMA prefetch clean but neutral -> staging latency not the critical path.
// R17: 8-wave TLP forces weight eviction (VGPR 40, FETCH 402MB). 3 waves/SIMD pinned.
// R18: per-tile atomic tile-stealing: +5us/tile cross-XCD atomic latency on the
//   critical path (k_edge 109us). Tail is <=1 tile skew (~2-3us) -> closed.
// R19 (this round): proven base + s_setprio(1) around l0/l1/l2g compute bursts
//   (T5). Blocks on a CU sit at independent phases; priority lets compute-phase
//   waves win issue slots over other blocks' staging. Predict k_edge ~49-50us.

template <int NK>
DI void load_wf2(const _Float16* __restrict__ wt, int Kp, int nbase, int l16, int q,
                 f16x8 f[NK][2]) {
#pragma unroll
    for (int nt = 0; nt < 2; ++nt) {
        int n = nbase + nt * 16 + l16;
#pragma unroll
        for (int ks = 0; ks < NK; ++ks)
            f[ks][nt] = *(const f16x8*)(wt + n * Kp + ks * 32 + q * 8);
    }
}

// Layer 0 over MH 16-row groups: H0' = relu(W0^T X^T), f16 to H0 (stride 136). BAR.
template <int NK0, int MH>
DI void l0(const f16x8 (*w0f)[2], const _Float16* __restrict__ X, int xstride,
           _Float16* __restrict__ H0, int l16, int nb, int q) {
    const f32x4 zero = {0.f, 0.f, 0.f, 0.f};
    f32x4 acc[2][MH];
#pragma unroll
    for (int nt = 0; nt < 2; ++nt)
#pragma unroll
        for (int mt = 0; mt < MH; ++mt) acc[nt][mt] = zero;
    __builtin_amdgcn_s_setprio(1);
#pragma unroll
    for (int ks = 0; ks < NK0; ++ks) {
        f16x8 x[MH];
#pragma unroll
        for (int mt = 0; mt < MH; ++mt)
            x[mt] = *(const f16x8*)(X + (mt * 16 + l16) * xstride + ks * 32 + q * 8);
#pragma unroll
        for (int nt = 0; nt < 2; ++nt)
#pragma unroll
            for (int mt = 0; mt < MH; ++mt)
                acc[nt][mt] = mfma16(w0f[ks][nt], x[mt], acc[nt][mt]);
    }
    __builtin_amdgcn_s_setprio(0);
#pragma unroll
    for (int mt = 0; mt < MH; ++mt)
#pragma unroll
        for (int nt = 0; nt < 2; ++nt) {
            f16x4 h;
#pragma unroll
            for (int i = 0; i < 4; ++i) h[i] = (_Float16)fmaxf(acc[nt][mt][i], 0.f);
            *(f16x4*)(H0 + (mt * 16 + l16) * 136 + nb + nt * 16 + q * 4) = h;
        }
    BAR();
}

// Layer 1: H1' = relu(W1^T H0^T), f16 to H1 (stride 136). BAR.
template <int MH>
DI void l1(const f16x8 (*w1f)[2], const _Float16* __restrict__ H0,
           _Float16* __restrict__ H1, int l16, int nb, int q) {
    const f32x4 zero = {0.f, 0.f, 0.f, 0.f};
    f32x4 a1[2][MH];
#pragma unroll
    for (int nt = 0; nt < 2; ++nt)
#pragma unroll
        for (int mt = 0; mt < MH; ++mt) a1[nt][mt] = zero;
    __builtin_amdgcn_s_setprio(1);
#pragma unroll
    for (int ks = 0; ks < 4; ++ks) {
        f16x8 x[MH];
#pragma unroll
        for (int mt = 0; mt < MH; ++mt)
            x[mt] = *(const f16x8*)(H0 + (mt * 16 + l16) * 136 + ks * 32 + q * 8);
#pragma unroll
        for (int nt = 0; nt < 2; ++nt)
#pragma unroll
            for (int mt = 0; mt < MH; ++mt)
                a1[nt][mt] = mfma16(w1f[ks][nt], x[mt], a1[nt][mt]);
    }
    __builtin_amdgcn_s_setprio(0);
#pragma unroll
    for (int mt = 0; mt < MH; ++mt)
#pragma unroll
        for (int nt = 0; nt < 2; ++nt) {
            f16x4 h;
#pragma unroll
            for (int i = 0; i < 4; ++i) h[i] = (_Float16)fmaxf(a1[nt][mt][i], 0.f);
            *(f16x4*)(H1 + (mt * 16 + l16) * 136 + nb + nt * 16 + q * 4) = h;
        }
    BAR();
}

// Layer 2, row group g: rows (w>>1)*16 + l16 + 32*g, cols (w&1)*16 + q*4 + i.
DI f32x4 l2g(const f16x8* w2f, const _Float16* __restrict__ H1, int l16, int w,
             int q, int g) {
    int m = (w >> 1) * 16 + l16 + 32 * g;
    f32x4 acc = {0.f, 0.f, 0.f, 0.f};
    __builtin_amdgcn_s_setprio(1);
#pragma unroll
    for (int ks = 0; ks < 4; ++ks) {
        f16x8 x = *(const f16x8*)(H1 + m * 136 + ks * 32 + q * 8);
        acc = mfma16(w2f[ks], x, acc);
    }
    __builtin_amdgcn_s_setprio(0);
    return acc;
}

// ---------------- weight prep: fp32 [K][N] -> f16 W^T [Np][Kp] (zero padded) ----
struct WPtrs { const float* p[15]; };

__global__ void k_prep(WPtrs wp, _Float16* __restrict__ ws) {
    int b = blockIdx.x;
    const float* src; int K, N, Np, Kp, off;
    if (b == 0)       { src = wp.p[0];  K = 3;   N = 128; Np = 128; Kp = 32;  off = 0; }
    else if (b == 1)  { src = wp.p[1];  K = 128; N = 128; Np = 128; Kp = 128; off = 4096; }
    else if (b == 2)  { src = wp.p[2];  K = 128; N = 32;  Np = 32;  Kp = 128; off = 20480; }
    else if (b == 3)  { src = wp.p[3];  K = 3;   N = 128; Np = 128; Kp = 32;  off = 24576; }
    else if (b == 4)  { src = wp.p[4];  K = 128; N = 128; Np = 128; Kp = 128; off = 28672; }
    else if (b == 5)  { src = wp.p[5];  K = 128; N = 32;  Np = 32;  Kp = 128; off = 45056; }
    else if (b <= 9)  { int t = b - 6;  src = wp.p[6] + t * 12288;  K = 96;  N = 128; Np = 128; Kp = 96;  off = 49152 + t * 32768; }
    else if (b <= 13) { int t = b - 10; src = wp.p[7] + t * 16384;  K = 128; N = 128; Np = 128; Kp = 128; off = 61440 + t * 32768; }
    else if (b <= 17) { int t = b - 14; src = wp.p[8] + t * 4096;   K = 128; N = 32;  Np = 32;  Kp = 128; off = 77824 + t * 32768; }
    else if (b <= 21) { int t = b - 18; src = wp.p[9] + t * 8192;   K = 64;  N = 128; Np = 128; Kp = 64;  off = 180224 + t * 28672; }
    else if (b <= 25) { int t = b - 22; src = wp.p[10] + t * 16384; K = 128; N = 128; Np = 128; Kp = 128; off = 188416 + t * 28672; }
    else if (b <= 29) { int t = b - 26; src = wp.p[11] + t * 4096;  K = 128; N = 32;  Np = 32;  Kp = 128; off = 204800 + t * 28672; }
    else if (b == 30) { src = wp.p[12]; K = 32;  N = 128; Np = 128; Kp = 32;  off = 294912; }
    else if (b == 31) { src = wp.p[13]; K = 128; N = 128; Np = 128; Kp = 128; off = 299008; }
    else              { src = wp.p[14]; K = 128; N = 1;   Np = 16;  Kp = 128; off = 315392; }
    int total = Np * Kp;
    for (int i = threadIdx.x; i < total; i += 256) {
        int n = i / Kp, k = i - n * Kp;
        float v = (k < K && n < N) ? src[k * N + n] : 0.f;
        ws[off + i] = (_Float16)v;
    }
}

// ---------------- CSR build: histogram -> scan -> scatter (u32 atomics only) -----
__global__ void k_zero(unsigned* __restrict__ p, int n) {
    int i = blockIdx.x * 256 + threadIdx.x;
    if (i < n) p[i] = 0u;
}
__global__ void k_hist(const int* __restrict__ gi, unsigned* __restrict__ cnt) {
    int e = blockIdx.x * 256 + threadIdx.x;
    if (e < 512000) atomicAdd(&cnt[gi[2 * e + 1]], 1u);
}
// one block, 1024 threads: exclusive scan of cnt[0..32000) via Kogge-Stone.
__global__ __launch_bounds__(1024) void k_scan(
    const unsigned* __restrict__ cnt, unsigned* __restrict__ rowptr,
    unsigned* __restrict__ cursor) {
    __shared__ unsigned s[1024];
    int t = threadIdx.x;
    unsigned loc[32];
    unsigned sum = 0;
#pragma unroll
    for (int i = 0; i < 32; ++i) {
        int idx = t * 32 + i;
        unsigned v = (idx < 32000) ? cnt[idx] : 0u;
        loc[i] = v; sum += v;
    }
    s[t] = sum;
    __syncthreads();
#pragma unroll
    for (int d = 1; d < 1024; d <<= 1) {
        unsigned x = (t >= d) ? s[t - d] : 0u;
        __syncthreads();
        s[t] += x;
        __syncthreads();
    }
    if (t == 1023) rowptr[32000] = s[1023];
    unsigned off = (t == 0) ? 0u : s[t - 1];
#pragma unroll
    for (int i = 0; i < 32; ++i) {
        int idx = t * 32 + i;
        if (idx < 32000) { rowptr[idx] = off; cursor[idx] = off; off += loc[i]; }
    }
}
__global__ void k_scatter(const int* __restrict__ gi, unsigned* __restrict__ cursor,
                          unsigned* __restrict__ iperm, int2* __restrict__ sr) {
    int e = blockIdx.x * 256 + threadIdx.x;
    if (e < 512000) {
        int s = gi[2 * e], r = gi[2 * e + 1];
        unsigned pos = atomicAdd(&cursor[r], 1u);
        iperm[pos] = (unsigned)e;
        sr[pos] = make_int2(s, r);
    }
}

// ---------------- encoder: fp32 [M][3] -> MLP -> f16 out rows (64-row tiles) -----
__global__ __launch_bounds__(256, 3) void k_enc(
    const float* __restrict__ in, _Float16* __restrict__ out,
    const _Float16* __restrict__ w0t, const _Float16* __restrict__ w1t,
    const _Float16* __restrict__ w2t, int NT, const unsigned* __restrict__ iperm) {
    __shared__ __align__(16) _Float16 Xp[64 * 40];
    __shared__ __align__(16) _Float16 H0[64 * 136];
    __shared__ __align__(16) _Float16 H1[64 * 136];
    const int tid = threadIdx.x, w = tid >> 6, lane = tid & 63;
    const int q = lane >> 4, l16 = lane & 15;
    f16x8 w0f[1][2], w1f[4][2], w2f[4];
    load_wf2<1>(w0t, 32, w * 32, l16, q, w0f);
    load_wf2<4>(w1t, 128, w * 32, l16, q, w1f);
    {
        int n2 = (w & 1) * 16 + l16;
#pragma unroll
        for (int ks = 0; ks < 4; ++ks)
            w2f[ks] = *(const f16x8*)(w2t + n2 * 128 + ks * 32 + q * 8);
    }
    for (int c = tid; c < 2560; c += 256) Xp[c] = (_Float16)0.f;
    BAR();

    const int g = gridDim.x;
    const int dr = tid / 3, dc = tid - dr * 3;  // valid when tid<192
    const int orow = (w >> 1) * 16 + l16, ocol = (w & 1) * 16 + q * 4;
    int t = blockIdx.x;

    while (true) {
        if (tid < 192) {
            unsigned e = iperm ? iperm[t * 64 + dr] : (unsigned)(t * 64 + dr);
            Xp[dr * 40 + dc] = (_Float16)in[e * 3 + dc];
        }
        BAR();
        l0<1, 4>(w0f, Xp, 40, H0, l16, w * 32, q);
        l1<4>(w1f, H0, H1, l16, w * 32, q);
#pragma unroll
        for (int gg = 0; gg < 2; ++gg) {
            f32x4 o = l2g(w2f, H1, l16, w, q, gg);
            f16x4 ov;
#pragma unroll
            for (int i = 0; i < 4; ++i) ov[i] = (_Float16)o[i];
            *(f16x4*)(out + (t * 64 + gg * 32 + orow) * 32 + ocol) = ov;
        }
        t += g;
        if (t >= NT) break;
    }
}

// ---------------- edge update: [edge|node_s|node_r](96) -> MLP -> +res -----------
// Exact proven R10 body: gathers at loop top (no reg/DMA prefetch), 3 barriers,
// padded Xe stride 104, blockIdx-strided persistent loop, grid 768.
__global__ __launch_bounds__(256, 3) void k_edge(
    const _Float16* __restrict__ node, _Float16* __restrict__ edgeP,
    const int2* __restrict__ sr,
    const _Float16* __restrict__ w0t, const _Float16* __restrict__ w1t,
    const _Float16* __restrict__ w2t) {
    __shared__ __align__(16) _Float16 Xe[64 * 104];
    __shared__ __align__(16) _Float16 H0[64 * 136];
    __shared__ __align__(16) _Float16 H1[64 * 136];
    const int tid = threadIdx.x, w = tid >> 6, lane = tid & 63;
    const int q = lane >> 4, l16 = lane & 15;
    f16x8 w0f[3][2], w1f[4][2], w2f[4];
    load_wf2<3>(w0t, 96, w * 32, l16, q, w0f);
    load_wf2<4>(w1t, 128, w * 32, l16, q, w1f);
    {
        int n2 = (w & 1) * 16 + l16;
#pragma unroll
        for (int ks = 0; ks < 4; ++ks)
            w2f[ks] = *(const f16x8*)(w2t + n2 * 128 + ks * 32 + q * 8);
    }
    int cr[3], cs[3];
#pragma unroll
    for (int j = 0; j < 3; ++j) {
        int c = tid + 256 * j;
        cr[j] = c / 12; cs[j] = c - cr[j] * 12;
    }
    const int orow = (w >> 1) * 16 + l16, ocol = (w & 1) * 16 + q * 4;

    const int NT = 8000, g = gridDim.x;
    int t = blockIdx.x;
    int2 srv[3];
#pragma unroll
    for (int j = 0; j < 3; ++j) srv[j] = sr[t * 64 + cr[j]];

    while (true) {
        int tn = t + g; if (tn >= NT) tn = t;
        // stage tile t (loads issue; Xe write waits on them via vmcnt)
        int4 v[3];
#pragma unroll
        for (int j = 0; j < 3; ++j) {
            int s = cs[j];
            const _Float16* src = (s < 4) ? edgeP + (t * 64 + cr[j]) * 32 + s * 8
                               : (s < 8) ? node + srv[j].x * 32 + (s - 4) * 8
                                         : node + srv[j].y * 32 + (s - 8) * 8;
            v[j] = *(const int4*)src;
        }
        int2 srn[3];
#pragma unroll
        for (int j = 0; j < 3; ++j) srn[j] = sr[tn * 64 + cr[j]];
#pragma unroll
        for (int j = 0; j < 3; ++j)
            *(int4*)(Xe + cr[j] * 104 + cs[j] * 8) = v[j];
        BAR();  // 1: Xe visible
        // old edge latent from LDS (cols 0..31 of the staged tile)
        f16x4 oldv[2];
#pragma unroll
        for (int gg = 0; gg < 2; ++gg)
            oldv[gg] = *(const f16x4*)(Xe + (gg * 32 + orow) * 104 + ocol);

        l0<3, 4>(w0f, Xe, 104, H0, l16, w * 32, q);  // BAR 2 inside
        l1<4>(w1f, H0, H1, l16, w * 32, q);          // BAR 3 inside
#pragma unroll
        for (int gg = 0; gg < 2; ++gg) {
            f32x4 o = l2g(w2f, H1, l16, w, q, gg);
            f16x4 nv;
#pragma unroll
            for (int i = 0; i < 4; ++i) nv[i] = (_Float16)(o[i] + (float)oldv[gg][i]);
            *(f16x4*)(edgeP + (t * 64 + gg * 32 + orow) * 32 + ocol) = nv;
        }

        if (tn == t) break;
        t = tn;
#pragma unroll
        for (int j = 0; j < 3; ++j) srv[j] = srn[j];
    }
}

// ---------------- node update: [node|csr_sum(edgeP)](64) -> MLP -> +res ----------
// One 32-row tile per block (proven variant, untouched).
__global__ __launch_bounds__(256, 3) void k_node(
    _Float16* __restrict__ node, const _Float16* __restrict__ edgeP,
    const unsigned* __restrict__ rowptr,
    const _Float16* __restrict__ w0t, const _Float16* __restrict__ w1t,
    const _Float16* __restrict__ w2t) {
    __shared__ __align__(16) _Float16 Xn[32 * 72];
    __shared__ __align__(16) _Float16 H0[32 * 136];
    __shared__ __align__(16) _Float16 H1[32 * 136];
    const int tid = threadIdx.x, w = tid >> 6, lane = tid & 63;
    const int q = lane >> 4, l16 = lane & 15;
    f16x8 w0f[2][2], w1f[4][2], w2f[4];
    load_wf2<2>(w0t, 64, w * 32, l16, q, w0f);
    load_wf2<4>(w1t, 128, w * 32, l16, q, w1f);
    {
        int n2 = (w & 1) * 16 + l16;
#pragma unroll
        for (int ks = 0; ks < 4; ++ks)
            w2f[ks] = *(const f16x8*)(w2t + n2 * 128 + ks * 32 + q * 8);
    }
    const int t = blockIdx.x;
    const int orow = (w >> 1) * 16 + l16, ocol = (w & 1) * 16 + q * 4;
    // 8 chunks/row (16 B each): cs<4 node copy, cs>=4 segment-sum of edgeP chunk
    {
        int cr = tid >> 3, cs = tid & 7;
        int r = t * 32 + cr;
        if (cs < 4) {
            *(int4*)(Xn + cr * 72 + cs * 8) = *(const int4*)(node + r * 32 + cs * 8);
        } else {
            unsigned b = rowptr[r], e = rowptr[r + 1];
            const _Float16* base = edgeP + (cs - 4) * 8;
            float a0[8], a1[8];
#pragma unroll
            for (int i = 0; i < 8; ++i) { a0[i] = 0.f; a1[i] = 0.f; }
            unsigned p = b;
            for (; p + 2 <= e; p += 2) {
                f16x8 x0 = *(const f16x8*)(base + (p + 0) * 32);
                f16x8 x1 = *(const f16x8*)(base + (p + 1) * 32);
#pragma unroll
                for (int i = 0; i < 8; ++i) { a0[i] += (float)x0[i]; a1[i] += (float)x1[i]; }
            }
            if (p < e) {
                f16x8 x0 = *(const f16x8*)(base + p * 32);
#pragma unroll
                for (int i = 0; i < 8; ++i) a0[i] += (float)x0[i];
            }
            f16x8 h;
#pragma unroll
            for (int i = 0; i < 8; ++i) h[i] = (_Float16)(a0[i] + a1[i]);
            *(f16x8*)(Xn + cr * 72 + cs * 8) = h;
        }
    }
    BAR();
    f16x4 oldv = *(const f16x4*)(Xn + orow * 72 + ocol);
    l0<2, 2>(w0f, Xn, 72, H0, l16, w * 32, q);
    l1<2>(w1f, H0, H1, l16, w * 32, q);
    f32x4 o = l2g(w2f, H1, l16, w, q, 0);
    f16x4 nv;
#pragma unroll
    for (int i = 0; i < 4; ++i) nv[i] = (_Float16)(o[i] + (float)oldv[i]);
    *(f16x4*)(node + (t * 32 + orow) * 32 + ocol) = nv;
}

// ---------------- decoder: node(32) -> MLP(32->128->128->1) -> fp32 out ----------
__global__ __launch_bounds__(256, 3) void k_dec(
    const _Float16* __restrict__ node,
    const _Float16* __restrict__ w0t, const _Float16* __restrict__ w1t,
    const _Float16* __restrict__ w2t, float* __restrict__ out) {
    __shared__ __align__(16) _Float16 Xd[64 * 40];
    __shared__ __align__(16) _Float16 H0[64 * 136];
    __shared__ __align__(16) _Float16 H1[64 * 136];
    const int tid = threadIdx.x, w = tid >> 6, lane = tid & 63;
    const int q = lane >> 4, l16 = lane & 15;
    f16x8 w0f[1][2], w1f[4][2], w2f[4];
    load_wf2<1>(w0t, 32, w * 32, l16, q, w0f);
    load_wf2<4>(w1t, 128, w * 32, l16, q, w1f);
    {
        int n2 = l16;  // padded W2^T is [16][128]; all waves load tile 0
#pragma unroll
        for (int ks = 0; ks < 4; ++ks)
            w2f[ks] = *(const f16x8*)(w2t + n2 * 128 + ks * 32 + q * 8);
    }
    const int t = blockIdx.x;
    {
        int cr = tid >> 2, cs = tid & 3;
        *(int4*)(Xd + cr * 40 + cs * 8) = *(const int4*)(node + (t * 64 + cr) * 32 + cs * 8);
    }
    BAR();
    l0<1, 4>(w0f, Xd, 40, H0, l16, w * 32, q);
    l1<4>(w1f, H0, H1, l16, w * 32, q);
#pragma unroll
    for (int gg = 0; gg < 2; ++gg) {
        f32x4 o = l2g(w2f, H1, l16, w, q, gg);
        // only col 0 is real: waves with (w&1)==0, lanes q==0, reg 0
        if ((w & 1) == 0 && q == 0) out[t * 64 + gg * 32 + (w >> 1) * 16 + l16] = o[0];
    }
}

extern "C" void kernel_launch(void* const* d_in, const int* in_sizes, int n_in,
                              void* d_out, int out_size, void* d_ws, size_t ws_size,
                              hipStream_t stream) {
    const float* input_node = (const float*)d_in[0];
    const float* input_edge = (const float*)d_in[1];
    const int* gi = (const int*)d_in[2];

    _Float16* ws = (_Float16*)d_ws;
    // ws layout (bytes):
    //   weights f16:         [0,          634,880)
    //   node  f16 32000x32:  [655,360,    2,703,360)
    //   edgeP f16 512000x32: [2,703,360,  35,471,360)   (receiver-sorted rows)
    //   rowptr u32[32001]:   [35,471,360, 35,599,364)
    //   cursor u32[32000]:   [35,599,616, 35,727,616)
    //   iperm  u32[512000]:  [35,727,616, 37,775,616)
    //   sr   int2[512000]:   [37,775,616, 41,871,616)
    _Float16* node = (_Float16*)((char*)d_ws + 655360);
    _Float16* edgeP = (_Float16*)((char*)d_ws + 2703360);
    unsigned* rowptr = (unsigned*)((char*)d_ws + 35471360);
    unsigned* cursor = (unsigned*)((char*)d_ws + 35599616);
    unsigned* iperm = (unsigned*)((char*)d_ws + 35727616);
    int2* sr = (int2*)((char*)d_ws + 37775616);

    WPtrs wp;
    for (int i = 0; i < 15; ++i) wp.p[i] = (const float*)d_in[3 + i];

    k_prep<<<33, 256, 0, stream>>>(wp, ws);

    // CSR build (u32 atomics only)
    k_zero<<<125, 256, 0, stream>>>(cursor, 32000);
    k_hist<<<2000, 256, 0, stream>>>(gi, cursor);
    k_scan<<<1, 1024, 0, stream>>>(cursor, rowptr, cursor);
    k_scatter<<<2000, 256, 0, stream>>>(gi, cursor, iperm, sr);

    k_enc<<<500, 256, 0, stream>>>(input_node, node, ws + 0, ws + 4096, ws + 20480,
                                   500, nullptr);
    k_enc<<<768, 256, 0, stream>>>(input_edge, edgeP, ws + 24576, ws + 28672,
                                   ws + 45056, 8000, iperm);

    for (int t = 0; t < 4; ++t) {
        k_edge<<<768, 256, 0, stream>>>(node, edgeP, sr,
                                        ws + 49152 + t * 32768,
                                        ws + 61440 + t * 32768,
                                        ws + 77824 + t * 32768);
        k_node<<<1000, 256, 0, stream>>>(node, edgeP, rowptr,
                                         ws + 180224 + t * 28672,
                                         ws + 188416 + t * 28672,
                                         ws + 204800 + t * 28672);
    }
    k_dec<<<500, 256, 0, stream>>>(node, ws + 294912, ws + 299008, ws + 315392,
                                   (float*)d_out);
}

// Round 9
// 448.916 us; speedup vs baseline: 2.0075x; 1.0953x over previous
//
#include <hip/hip_runtime.h>

typedef __attribute__((ext_vector_type(8))) _Float16 f16x8;
typedef __attribute__((ext_vector_type(4))) _Float16 f16x4;
typedef __attribute__((ext_vector_type(4))) float f32x4;

#define DI __device__ __forceinline__
// Raw barrier: LDS-drain only (lgkmcnt). Avoids the compiler's vmcnt(0) drain.
#define BAR() asm volatile("s_waitcnt lgkmcnt(0)\n\ts_barrier" ::: "memory")

DI f32x4 mfma16(f16x8 a, f16x8 b, f32x4 c) {
    return __builtin_amdgcn_mfma_f32_16x16x32_f16(a, b, c, 0, 0, 0);
}

// Wave-mapping (4-wave kernels): wave w owns features [w*32, w*32+32) for layers
// 0/1; layer 2: wave w -> rows (w>>1)*16 (+32*g), cols (w&1)*16.
// PROVEN STATE (R19, 491.7 us): R10 structure + s_setprio(1) around MFMA bursts.
// R11: lb(256,4) caps regs at 128 -> weights evicted -> regression.
// R12: 64-row k_node diverged intermittently under graph replay -> revert.
// R13/R15: register-held gather prefetch spills regardless of waves_per_eu.
// R14: LDS shrink for 4 blk/CU: achieved occupancy FELL; extra BAR -5%.
// R16: DMA prefetch clean but neutral -> staging latency not the critical path.
// R17: 8-wave TLP forces weight eviction. 3 waves/SIMD pinned by weights.
// R18: per-tile atomic tile-stealing: cross-XCD atomic latency >> tail. Closed.
// R19: setprio(1) on l0/l1/l2g: 502->492us (T5 confirmed). KEEP.
// R20 (this round): k_scan was 51us serial on ONE CU (0.125% occupancy, 10% of
//   wall). Replaced by 3-phase parallel scan over 125 blocks (block-scan ->
//   top-scan of 125 totals -> add offsets). bsum[125] borrows iperm space
//   (written later by k_scatter; stream-serial). Predict total ~450-458us.

template <int NK>
DI void load_wf2(const _Float16* __restrict__ wt, int Kp, int nbase, int l16, int q,
                 f16x8 f[NK][2]) {
#pragma unroll
    for (int nt = 0; nt < 2; ++nt) {
        int n = nbase + nt * 16 + l16;
#pragma unroll
        for (int ks = 0; ks < NK; ++ks)
            f[ks][nt] = *(const f16x8*)(wt + n * Kp + ks * 32 + q * 8);
    }
}

// Layer 0 over MH 16-row groups: H0' = relu(W0^T X^T), f16 to H0 (stride 136). BAR.
template <int NK0, int MH>
DI void l0(const f16x8 (*w0f)[2], const _Float16* __restrict__ X, int xstride,
           _Float16* __restrict__ H0, int l16, int nb, int q) {
    const f32x4 zero = {0.f, 0.f, 0.f, 0.f};
    f32x4 acc[2][MH];
#pragma unroll
    for (int nt = 0; nt < 2; ++nt)
#pragma unroll
        for (int mt = 0; mt < MH; ++mt) acc[nt][mt] = zero;
    __builtin_amdgcn_s_setprio(1);
#pragma unroll
    for (int ks = 0; ks < NK0; ++ks) {
        f16x8 x[MH];
#pragma unroll
        for (int mt = 0; mt < MH; ++mt)
            x[mt] = *(const f16x8*)(X + (mt * 16 + l16) * xstride + ks * 32 + q * 8);
#pragma unroll
        for (int nt = 0; nt < 2; ++nt)
#pragma unroll
            for (int mt = 0; mt < MH; ++mt)
                acc[nt][mt] = mfma16(w0f[ks][nt], x[mt], acc[nt][mt]);
    }
    __builtin_amdgcn_s_setprio(0);
#pragma unroll
    for (int mt = 0; mt < MH; ++mt)
#pragma unroll
        for (int nt = 0; nt < 2; ++nt) {
            f16x4 h;
#pragma unroll
            for (int i = 0; i < 4; ++i) h[i] = (_Float16)fmaxf(acc[nt][mt][i], 0.f);
            *(f16x4*)(H0 + (mt * 16 + l16) * 136 + nb + nt * 16 + q * 4) = h;
        }
    BAR();
}

// Layer 1: H1' = relu(W1^T H0^T), f16 to H1 (stride 136). BAR.
template <int MH>
DI void l1(const f16x8 (*w1f)[2], const _Float16* __restrict__ H0,
           _Float16* __restrict__ H1, int l16, int nb, int q) {
    const f32x4 zero = {0.f, 0.f, 0.f, 0.f};
    f32x4 a1[2][MH];
#pragma unroll
    for (int nt = 0; nt < 2; ++nt)
#pragma unroll
        for (int mt = 0; mt < MH; ++mt) a1[nt][mt] = zero;
    __builtin_amdgcn_s_setprio(1);
#pragma unroll
    for (int ks = 0; ks < 4; ++ks) {
        f16x8 x[MH];
#pragma unroll
        for (int mt = 0; mt < MH; ++mt)
            x[mt] = *(const f16x8*)(H0 + (mt * 16 + l16) * 136 + ks * 32 + q * 8);
#pragma unroll
        for (int nt = 0; nt < 2; ++nt)
#pragma unroll
            for (int mt = 0; mt < MH; ++mt)
                a1[nt][mt] = mfma16(w1f[ks][nt], x[mt], a1[nt][mt]);
    }
    __builtin_amdgcn_s_setprio(0);
#pragma unroll
    for (int mt = 0; mt < MH; ++mt)
#pragma unroll
        for (int nt = 0; nt < 2; ++nt) {
            f16x4 h;
#pragma unroll
            for (int i = 0; i < 4; ++i) h[i] = (_Float16)fmaxf(a1[nt][mt][i], 0.f);
            *(f16x4*)(H1 + (mt * 16 + l16) * 136 + nb + nt * 16 + q * 4) = h;
        }
    BAR();
}

// Layer 2, row group g: rows (w>>1)*16 + l16 + 32*g, cols (w&1)*16 + q*4 + i.
DI f32x4 l2g(const f16x8* w2f, const _Float16* __restrict__ H1, int l16, int w,
             int q, int g) {
    int m = (w >> 1) * 16 + l16 + 32 * g;
    f32x4 acc = {0.f, 0.f, 0.f, 0.f};
    __builtin_amdgcn_s_setprio(1);
#pragma unroll
    for (int ks = 0; ks < 4; ++ks) {
        f16x8 x = *(const f16x8*)(H1 + m * 136 + ks * 32 + q * 8);
        acc = mfma16(w2f[ks], x, acc);
    }
    __builtin_amdgcn_s_setprio(0);
    return acc;
}

// ---------------- weight prep: fp32 [K][N] -> f16 W^T [Np][Kp] (zero padded) ----
struct WPtrs { const float* p[15]; };

__global__ void k_prep(WPtrs wp, _Float16* __restrict__ ws) {
    int b = blockIdx.x;
    const float* src; int K, N, Np, Kp, off;
    if (b == 0)       { src = wp.p[0];  K = 3;   N = 128; Np = 128; Kp = 32;  off = 0; }
    else if (b == 1)  { src = wp.p[1];  K = 128; N = 128; Np = 128; Kp = 128; off = 4096; }
    else if (b == 2)  { src = wp.p[2];  K = 128; N = 32;  Np = 32;  Kp = 128; off = 20480; }
    else if (b == 3)  { src = wp.p[3];  K = 3;   N = 128; Np = 128; Kp = 32;  off = 24576; }
    else if (b == 4)  { src = wp.p[4];  K = 128; N = 128; Np = 128; Kp = 128; off = 28672; }
    else if (b == 5)  { src = wp.p[5];  K = 128; N = 32;  Np = 32;  Kp = 128; off = 45056; }
    else if (b <= 9)  { int t = b - 6;  src = wp.p[6] + t * 12288;  K = 96;  N = 128; Np = 128; Kp = 96;  off = 49152 + t * 32768; }
    else if (b <= 13) { int t = b - 10; src = wp.p[7] + t * 16384;  K = 128; N = 128; Np = 128; Kp = 128; off = 61440 + t * 32768; }
    else if (b <= 17) { int t = b - 14; src = wp.p[8] + t * 4096;   K = 128; N = 32;  Np = 32;  Kp = 128; off = 77824 + t * 32768; }
    else if (b <= 21) { int t = b - 18; src = wp.p[9] + t * 8192;   K = 64;  N = 128; Np = 128; Kp = 64;  off = 180224 + t * 28672; }
    else if (b <= 25) { int t = b - 22; src = wp.p[10] + t * 16384; K = 128; N = 128; Np = 128; Kp = 128; off = 188416 + t * 28672; }
    else if (b <= 29) { int t = b - 26; src = wp.p[11] + t * 4096;  K = 128; N = 32;  Np = 32;  Kp = 128; off = 204800 + t * 28672; }
    else if (b == 30) { src = wp.p[12]; K = 32;  N = 128; Np = 128; Kp = 32;  off = 294912; }
    else if (b == 31) { src = wp.p[13]; K = 128; N = 128; Np = 128; Kp = 128; off = 299008; }
    else              { src = wp.p[14]; K = 128; N = 1;   Np = 16;  Kp = 128; off = 315392; }
    int total = Np * Kp;
    for (int i = threadIdx.x; i < total; i += 256) {
        int n = i / Kp, k = i - n * Kp;
        float v = (k < K && n < N) ? src[k * N + n] : 0.f;
        ws[off + i] = (_Float16)v;
    }
}

// ---------------- CSR build: histogram -> 3-phase scan -> scatter ---------------
__global__ void k_zero(unsigned* __restrict__ p, int n) {
    int i = blockIdx.x * 256 + threadIdx.x;
    if (i < n) p[i] = 0u;
}
__global__ void k_hist(const int* __restrict__ gi, unsigned* __restrict__ cnt) {
    int e = blockIdx.x * 256 + threadIdx.x;
    if (e < 512000) atomicAdd(&cnt[gi[2 * e + 1]], 1u);
}
// Phase 1: 125 blocks x 256: in-block exclusive scan; rowptr[i] = local excl;
// bsum[b] = block total.
__global__ void k_scan_blk(const unsigned* __restrict__ cnt,
                           unsigned* __restrict__ rowptr,
                           unsigned* __restrict__ bsum) {
    __shared__ unsigned s[256];
    const int b = blockIdx.x, t = threadIdx.x;
    const int i = b * 256 + t;
    unsigned v = cnt[i];
    s[t] = v;
    __syncthreads();
#pragma unroll
    for (int d = 1; d < 256; d <<= 1) {
        unsigned x = (t >= d) ? s[t - d] : 0u;
        __syncthreads();
        s[t] += x;
        __syncthreads();
    }
    rowptr[i] = s[t] - v;  // exclusive within block
    if (t == 255) bsum[b] = s[255];
}
// Phase 2: 1 block x 128: exclusive scan of the 125 block totals; total->rowptr[32000].
__global__ void k_scan_top(unsigned* __restrict__ bsum,
                           unsigned* __restrict__ rowptr) {
    __shared__ unsigned s[128];
    const int t = threadIdx.x;
    unsigned v = (t < 125) ? bsum[t] : 0u;
    s[t] = v;
    __syncthreads();
#pragma unroll
    for (int d = 1; d < 128; d <<= 1) {
        unsigned x = (t >= d) ? s[t - d] : 0u;
        __syncthreads();
        s[t] += x;
        __syncthreads();
    }
    if (t < 125) bsum[t] = s[t] - v;  // exclusive block offset
    if (t == 127) rowptr[32000] = s[127];
}
// Phase 3: 125 blocks x 256: add block offset; final rowptr + cursor.
__global__ void k_scan_add(const unsigned* __restrict__ bsum,
                           unsigned* __restrict__ rowptr,
                           unsigned* __restrict__ cursor) {
    const int b = blockIdx.x, t = threadIdx.x;
    const int i = b * 256 + t;
    unsigned v = rowptr[i] + bsum[b];
    rowptr[i] = v;
    cursor[i] = v;
}
__global__ void k_scatter(const int* __restrict__ gi, unsigned* __restrict__ cursor,
                          unsigned* __restrict__ iperm, int2* __restrict__ sr) {
    int e = blockIdx.x * 256 + threadIdx.x;
    if (e < 512000) {
        int s = gi[2 * e], r = gi[2 * e + 1];
        unsigned pos = atomicAdd(&cursor[r], 1u);
        iperm[pos] = (unsigned)e;
        sr[pos] = make_int2(s, r);
    }
}

// ---------------- encoder: fp32 [M][3] -> MLP -> f16 out rows (64-row tiles) -----
__global__ __launch_bounds__(256, 3) void k_enc(
    const float* __restrict__ in, _Float16* __restrict__ out,
    const _Float16* __restrict__ w0t, const _Float16* __restrict__ w1t,
    const _Float16* __restrict__ w2t, int NT, const unsigned* __restrict__ iperm) {
    __shared__ __align__(16) _Float16 Xp[64 * 40];
    __shared__ __align__(16) _Float16 H0[64 * 136];
    __shared__ __align__(16) _Float16 H1[64 * 136];
    const int tid = threadIdx.x, w = tid >> 6, lane = tid & 63;
    const int q = lane >> 4, l16 = lane & 15;
    f16x8 w0f[1][2], w1f[4][2], w2f[4];
    load_wf2<1>(w0t, 32, w * 32, l16, q, w0f);
    load_wf2<4>(w1t, 128, w * 32, l16, q, w1f);
    {
        int n2 = (w & 1) * 16 + l16;
#pragma unroll
        for (int ks = 0; ks < 4; ++ks)
            w2f[ks] = *(const f16x8*)(w2t + n2 * 128 + ks * 32 + q * 8);
    }
    for (int c = tid; c < 2560; c += 256) Xp[c] = (_Float16)0.f;
    BAR();

    const int g = gridDim.x;
    const int dr = tid / 3, dc = tid - dr * 3;  // valid when tid<192
    const int orow = (w >> 1) * 16 + l16, ocol = (w & 1) * 16 + q * 4;
    int t = blockIdx.x;

    while (true) {
        if (tid < 192) {
            unsigned e = iperm ? iperm[t * 64 + dr] : (unsigned)(t * 64 + dr);
            Xp[dr * 40 + dc] = (_Float16)in[e * 3 + dc];
        }
        BAR();
        l0<1, 4>(w0f, Xp, 40, H0, l16, w * 32, q);
        l1<4>(w1f, H0, H1, l16, w * 32, q);
#pragma unroll
        for (int gg = 0; gg < 2; ++gg) {
            f32x4 o = l2g(w2f, H1, l16, w, q, gg);
            f16x4 ov;
#pragma unroll
            for (int i = 0; i < 4; ++i) ov[i] = (_Float16)o[i];
            *(f16x4*)(out + (t * 64 + gg * 32 + orow) * 32 + ocol) = ov;
        }
        t += g;
        if (t >= NT) break;
    }
}

// ---------------- edge update: [edge|node_s|node_r](96) -> MLP -> +res -----------
// Exact proven R10 body + setprio: gathers at loop top, 3 barriers, padded Xe
// stride 104, blockIdx-strided persistent loop, grid 768.
__global__ __launch_bounds__(256, 3) void k_edge(
    const _Float16* __restrict__ node, _Float16* __restrict__ edgeP,
    const int2* __restrict__ sr,
    const _Float16* __restrict__ w0t, const _Float16* __restrict__ w1t,
    const _Float16* __restrict__ w2t) {
    __shared__ __align__(16) _Float16 Xe[64 * 104];
    __shared__ __align__(16) _Float16 H0[64 * 136];
    __shared__ __align__(16) _Float16 H1[64 * 136];
    const int tid = threadIdx.x, w = tid >> 6, lane = tid & 63;
    const int q = lane >> 4, l16 = lane & 15;
    f16x8 w0f[3][2], w1f[4][2], w2f[4];
    load_wf2<3>(w0t, 96, w * 32, l16, q, w0f);
    load_wf2<4>(w1t, 128, w * 32, l16, q, w1f);
    {
        int n2 = (w & 1) * 16 + l16;
#pragma unroll
        for (int ks = 0; ks < 4; ++ks)
            w2f[ks] = *(const f16x8*)(w2t + n2 * 128 + ks * 32 + q * 8);
    }
    int cr[3], cs[3];
#pragma unroll
    for (int j = 0; j < 3; ++j) {
        int c = tid + 256 * j;
        cr[j] = c / 12; cs[j] = c - cr[j] * 12;
    }
    const int orow = (w >> 1) * 16 + l16, ocol = (w & 1) * 16 + q * 4;

    const int NT = 8000, g = gridDim.x;
    int t = blockIdx.x;
    int2 srv[3];
#pragma unroll
    for (int j = 0; j < 3; ++j) srv[j] = sr[t * 64 + cr[j]];

    while (true) {
        int tn = t + g; if (tn >= NT) tn = t;
        // stage tile t (loads issue; Xe write waits on them via vmcnt)
        int4 v[3];
#pragma unroll
        for (int j = 0; j < 3; ++j) {
            int s = cs[j];
            const _Float16* src = (s < 4) ? edgeP + (t * 64 + cr[j]) * 32 + s * 8
                               : (s < 8) ? node + srv[j].x * 32 + (s - 4) * 8
                                         : node + srv[j].y * 32 + (s - 8) * 8;
            v[j] = *(const int4*)src;
        }
        int2 srn[3];
#pragma unroll
        for (int j = 0; j < 3; ++j) srn[j] = sr[tn * 64 + cr[j]];
#pragma unroll
        for (int j = 0; j < 3; ++j)
            *(int4*)(Xe + cr[j] * 104 + cs[j] * 8) = v[j];
        BAR();  // 1: Xe visible
        // old edge latent from LDS (cols 0..31 of the staged tile)
        f16x4 oldv[2];
#pragma unroll
        for (int gg = 0; gg < 2; ++gg)
            oldv[gg] = *(const f16x4*)(Xe + (gg * 32 + orow) * 104 + ocol);

        l0<3, 4>(w0f, Xe, 104, H0, l16, w * 32, q);  // BAR 2 inside
        l1<4>(w1f, H0, H1, l16, w * 32, q);          // BAR 3 inside
#pragma unroll
        for (int gg = 0; gg < 2; ++gg) {
            f32x4 o = l2g(w2f, H1, l16, w, q, gg);
            f16x4 nv;
#pragma unroll
            for (int i = 0; i < 4; ++i) nv[i] = (_Float16)(o[i] + (float)oldv[gg][i]);
            *(f16x4*)(edgeP + (t * 64 + gg * 32 + orow) * 32 + ocol) = nv;
        }

        if (tn == t) break;
        t = tn;
#pragma unroll
        for (int j = 0; j < 3; ++j) srv[j] = srn[j];
    }
}

// ---------------- node update: [node|csr_sum(edgeP)](64) -> MLP -> +res ----------
// One 32-row tile per block (proven variant, untouched).
__global__ __launch_bounds__(256, 3) void k_node(
    _Float16* __restrict__ node, const _Float16* __restrict__ edgeP,
    const unsigned* __restrict__ rowptr,
    const _Float16* __restrict__ w0t, const _Float16* __restrict__ w1t,
    const _Float16* __restrict__ w2t) {
    __shared__ __align__(16) _Float16 Xn[32 * 72];
    __shared__ __align__(16) _Float16 H0[32 * 136];
    __shared__ __align__(16) _Float16 H1[32 * 136];
    const int tid = threadIdx.x, w = tid >> 6, lane = tid & 63;
    const int q = lane >> 4, l16 = lane & 15;
    f16x8 w0f[2][2], w1f[4][2], w2f[4];
    load_wf2<2>(w0t, 64, w * 32, l16, q, w0f);
    load_wf2<4>(w1t, 128, w * 32, l16, q, w1f);
    {
        int n2 = (w & 1) * 16 + l16;
#pragma unroll
        for (int ks = 0; ks < 4; ++ks)
            w2f[ks] = *(const f16x8*)(w2t + n2 * 128 + ks * 32 + q * 8);
    }
    const int t = blockIdx.x;
    const int orow = (w >> 1) * 16 + l16, ocol = (w & 1) * 16 + q * 4;
    // 8 chunks/row (16 B each): cs<4 node copy, cs>=4 segment-sum of edgeP chunk
    {
        int cr = tid >> 3, cs = tid & 7;
        int r = t * 32 + cr;
        if (cs < 4) {
            *(int4*)(Xn + cr * 72 + cs * 8) = *(const int4*)(node + r * 32 + cs * 8);
        } else {
            unsigned b = rowptr[r], e = rowptr[r + 1];
            const _Float16* base = edgeP + (cs - 4) * 8;
            float a0[8], a1[8];
#pragma unroll
            for (int i = 0; i < 8; ++i) { a0[i] = 0.f; a1[i] = 0.f; }
            unsigned p = b;
            for (; p + 2 <= e; p += 2) {
                f16x8 x0 = *(const f16x8*)(base + (p + 0) * 32);
                f16x8 x1 = *(const f16x8*)(base + (p + 1) * 32);
#pragma unroll
                for (int i = 0; i < 8; ++i) { a0[i] += (float)x0[i]; a1[i] += (float)x1[i]; }
            }
            if (p < e) {
                f16x8 x0 = *(const f16x8*)(base + p * 32);
#pragma unroll
                for (int i = 0; i < 8; ++i) a0[i] += (float)x0[i];
            }
            f16x8 h;
#pragma unroll
            for (int i = 0; i < 8; ++i) h[i] = (_Float16)(a0[i] + a1[i]);
            *(f16x8*)(Xn + cr * 72 + cs * 8) = h;
        }
    }
    BAR();
    f16x4 oldv = *(const f16x4*)(Xn + orow * 72 + ocol);
    l0<2, 2>(w0f, Xn, 72, H0, l16, w * 32, q);
    l1<2>(w1f, H0, H1, l16, w * 32, q);
    f32x4 o = l2g(w2f, H1, l16, w, q, 0);
    f16x4 nv;
#pragma unroll
    for (int i = 0; i < 4; ++i) nv[i] = (_Float16)(o[i] + (float)oldv[i]);
    *(f16x4*)(node + (t * 32 + orow) * 32 + ocol) = nv;
}

// ---------------- decoder: node(32) -> MLP(32->128->128->1) -> fp32 out ----------
__global__ __launch_bounds__(256, 3) void k_dec(
    const _Float16* __restrict__ node,
    const _Float16* __restrict__ w0t, const _Float16* __restrict__ w1t,
    const _Float16* __restrict__ w2t, float* __restrict__ out) {
    __shared__ __align__(16) _Float16 Xd[64 * 40];
    __shared__ __align__(16) _Float16 H0[64 * 136];
    __shared__ __align__(16) _Float16 H1[64 * 136];
    const int tid = threadIdx.x, w = tid >> 6, lane = tid & 63;
    const int q = lane >> 4, l16 = lane & 15;
    f16x8 w0f[1][2], w1f[4][2], w2f[4];
    load_wf2<1>(w0t, 32, w * 32, l16, q, w0f);
    load_wf2<4>(w1t, 128, w * 32, l16, q, w1f);
    {
        int n2 = l16;  // padded W2^T is [16][128]; all waves load tile 0
#pragma unroll
        for (int ks = 0; ks < 4; ++ks)
            w2f[ks] = *(const f16x8*)(w2t + n2 * 128 + ks * 32 + q * 8);
    }
    const int t = blockIdx.x;
    {
        int cr = tid >> 2, cs = tid & 3;
        *(int4*)(Xd + cr * 40 + cs * 8) = *(const int4*)(node + (t * 64 + cr) * 32 + cs * 8);
    }
    BAR();
    l0<1, 4>(w0f, Xd, 40, H0, l16, w * 32, q);
    l1<4>(w1f, H0, H1, l16, w * 32, q);
#pragma unroll
    for (int gg = 0; gg < 2; ++gg) {
        f32x4 o = l2g(w2f, H1, l16, w, q, gg);
        // only col 0 is real: waves with (w&1)==0, lanes q==0, reg 0
        if ((w & 1) == 0 && q == 0) out[t * 64 + gg * 32 + (w >> 1) * 16 + l16] = o[0];
    }
}

extern "C" void kernel_launch(void* const* d_in, const int* in_sizes, int n_in,
                              void* d_out, int out_size, void* d_ws, size_t ws_size,
                              hipStream_t stream) {
    const float* input_node = (const float*)d_in[0];
    const float* input_edge = (const float*)d_in[1];
    const int* gi = (const int*)d_in[2];

    _Float16* ws = (_Float16*)d_ws;
    // ws layout (bytes):
    //   weights f16:         [0,          634,880)
    //   node  f16 32000x32:  [655,360,    2,703,360)
    //   edgeP f16 512000x32: [2,703,360,  35,471,360)   (receiver-sorted rows)
    //   rowptr u32[32001]:   [35,471,360, 35,599,364)
    //   cursor u32[32000]:   [35,599,616, 35,727,616)
    //   iperm  u32[512000]:  [35,727,616, 37,775,616)   (first 500B double as bsum)
    //   sr   int2[512000]:   [37,775,616, 41,871,616)
    _Float16* node = (_Float16*)((char*)d_ws + 655360);
    _Float16* edgeP = (_Float16*)((char*)d_ws + 2703360);
    unsigned* rowptr = (unsigned*)((char*)d_ws + 35471360);
    unsigned* cursor = (unsigned*)((char*)d_ws + 35599616);
    unsigned* iperm = (unsigned*)((char*)d_ws + 35727616);
    int2* sr = (int2*)((char*)d_ws + 37775616);
    unsigned* bsum = iperm;  // borrowed until k_scatter (stream-serial)

    WPtrs wp;
    for (int i = 0; i < 15; ++i) wp.p[i] = (const float*)d_in[3 + i];

    k_prep<<<33, 256, 0, stream>>>(wp, ws);

    // CSR build (u32 atomics only), 3-phase parallel scan
    k_zero<<<125, 256, 0, stream>>>(cursor, 32000);
    k_hist<<<2000, 256, 0, stream>>>(gi, cursor);
    k_scan_blk<<<125, 256, 0, stream>>>(cursor, rowptr, bsum);
    k_scan_top<<<1, 128, 0, stream>>>(bsum, rowptr);
    k_scan_add<<<125, 256, 0, stream>>>(bsum, rowptr, cursor);
    k_scatter<<<2000, 256, 0, stream>>>(gi, cursor, iperm, sr);

    k_enc<<<500, 256, 0, stream>>>(input_node, node, ws + 0, ws + 4096, ws + 20480,
                                   500, nullptr);
    k_enc<<<768, 256, 0, stream>>>(input_edge, edgeP, ws + 24576, ws + 28672,
                                   ws + 45056, 8000, iperm);

    for (int t = 0; t < 4; ++t) {
        k_edge<<<768, 256, 0, stream>>>(node, edgeP, sr,
                                        ws + 49152 + t * 32768,
                                        ws + 61440 + t * 32768,
                                        ws + 77824 + t * 32768);
        k_node<<<1000, 256, 0, stream>>>(node, edgeP, rowptr,
                                         ws + 180224 + t * 28672,
                                         ws + 188416 + t * 28672,
                                         ws + 204800 + t * 28672);
    }
    k_dec<<<500, 256, 0, stream>>>(node, ws + 294912, ws + 299008, ws + 315392,
                                   (float*)d_out);
}